// Round 6
// baseline (359.005 us; speedup 1.0000x reference)
//
#include <hip/hip_runtime.h>

typedef float f32x4 __attribute__((ext_vector_type(4)));
typedef short bf16x8 __attribute__((ext_vector_type(8)));

__device__ inline unsigned short f2bf(float f) {
    unsigned int u = __builtin_bit_cast(unsigned int, f);
    unsigned int r = (u + 0x7FFFu + ((u >> 16) & 1u)) >> 16;
    return (unsigned short)r;
}

// ---------------- Combined prep: tok->bf16 | W transpose->bf16 | carr vectors
__global__ __launch_bounds__(256) void k_prep(const float* __restrict__ tok,
                                              const float* __restrict__ W,
                                              const float* __restrict__ dep,
                                              const float* __restrict__ idx,
                                              const float* __restrict__ bvec,
                                              unsigned short* __restrict__ tokbf,
                                              unsigned short* __restrict__ WTbf,
                                              float* __restrict__ carr) {
    __shared__ float s_tile[64][65];
    int bx = blockIdx.x;
    if (bx < 256) {
        int i = bx * 256 + threadIdx.x;
        const float4 v = *(const float4*)(tok + (long)i * 4);
        ushort4 o;
        o.x = f2bf(v.x); o.y = f2bf(v.y); o.z = f2bf(v.z); o.w = f2bf(v.w);
        *(ushort4*)(tokbf + (long)i * 4) = o;
    } else if (bx < 304) {
        int bb = bx - 256;
        int sec = bb >> 4;
        int tt = bb & 15;
        int k0 = (tt >> 2) * 64, j0 = (tt & 3) * 64;
        int tx = threadIdx.x & 63, ty = threadIdx.x >> 6;
#pragma unroll
        for (int r = 0; r < 16; r++) {
            int kk = ty * 16 + r;
            s_tile[kk][tx] = W[(sec * 256 + k0 + kk) * 256 + j0 + tx];
        }
        __syncthreads();
#pragma unroll
        for (int r = 0; r < 16; r++) {
            int jj = ty * 16 + r;
            WTbf[(sec * 256 + j0 + jj) * 256 + k0 + tx] = f2bf(s_tile[tx][jj]);
        }
    } else {
        int d = bx - 304;
        int j = threadIdx.x;
        float acc = bvec[j];
#pragma unroll 4
        for (int k = 0; k < 256; k++) {
            float dv = dep[(d + 1) * 256 + k];
            acc += dv * (W[(768 + k) * 256 + j] + W[(1280 + k) * 256 + j]);
            acc += idx[k] * W[(1024 + k) * 256 + j];
            acc += idx[256 + k] * W[(1536 + k) * 256 + j];
        }
        if (d == 13) {
#pragma unroll 4
            for (int k = 0; k < 256; k++) {
                float dv = dep[14 * 256 + k];
                acc += dv * (W[(256 + k) * 256 + j] + W[(512 + k) * 256 + j]);
            }
        }
        carr[d * 256 + j] = acc;
    }
}

// ---------------- T tables via MFMA: T[sec][1024][256] = tokbf @ Wsec
__global__ __launch_bounds__(256) void k_ttmm(const unsigned short* __restrict__ tokbf,
                                              const unsigned short* __restrict__ WTbf,
                                              float* __restrict__ T) {
    int wid = threadIdx.x >> 6, lane = threadIdx.x & 63;
    int l15 = lane & 15, l4 = lane >> 4;
    int row0 = blockIdx.x * 32;
    int sec = blockIdx.y;

    f32x4 acc[2][4] = {};
    for (int kk = 0; kk < 8; kk++) {
        int k0 = kk * 32 + l4 * 8;
        bf16x8 af[2], bfr[4];
#pragma unroll
        for (int mi = 0; mi < 2; mi++)
            af[mi] = *(const bf16x8*)(tokbf + (long)(row0 + mi * 16 + l15) * 256 + k0);
#pragma unroll
        for (int ni = 0; ni < 4; ni++)
            bfr[ni] = *(const bf16x8*)(WTbf + (long)(sec * 256 + wid * 64 + ni * 16 + l15) * 256 + k0);
#pragma unroll
        for (int mi = 0; mi < 2; mi++)
#pragma unroll
            for (int ni = 0; ni < 4; ni++)
                acc[mi][ni] = __builtin_amdgcn_mfma_f32_16x16x32_bf16(af[mi], bfr[ni],
                                                                     acc[mi][ni], 0, 0, 0);
    }
#pragma unroll
    for (int mi = 0; mi < 2; mi++)
#pragma unroll
        for (int r = 0; r < 4; r++) {
            int row = row0 + mi * 16 + l4 * 4 + r;
#pragma unroll
            for (int ni = 0; ni < 4; ni++) {
                int c = wid * 64 + ni * 16 + l15;
                T[(long)sec * 262144 + (long)row * 256 + c] = acc[mi][ni][r];
            }
        }
}

// ---------------- Fused level 13+12
__global__ __launch_bounds__(256) void k_level12f(const int* __restrict__ leaf_ids,
                                                  const int* __restrict__ op_ids,
                                                  const float* __restrict__ T,
                                                  const float* __restrict__ carr,
                                                  const float* __restrict__ gamma,
                                                  const float* __restrict__ beta,
                                                  const unsigned short* __restrict__ WTbf,
                                                  unsigned short* __restrict__ ebuf_out) {
    __shared__ unsigned short sA[128 * 256];
    __shared__ int s_nid13[128];
    __shared__ int s_leaf[256];
    __shared__ int s_nid[64];
    __shared__ float s_part[4][64][2];
    int b = blockIdx.y;
    int row0 = blockIdx.x * 64;
    int t = threadIdx.x;
    int wid = t >> 6, lane = t & 63;
    int l15 = lane & 15, l4 = lane >> 4;
    const float* T0 = T;
    const float* T1 = T + 262144;
    const float* T2 = T + 524288;

    if (t < 128) s_nid13[t] = op_ids[b * 16383 + 8191 + 2 * row0 + t];
    s_leaf[t] = leaf_ids[b * 16384 + 4 * row0 + t];
    if (t < 64) s_nid[t] = op_ids[b * 16383 + 4095 + row0 + t];
    __syncthreads();

    {
        const float* c13 = carr + 13 * 256;
        float4 dd = *(const float4*)(c13 + 4 * lane);
        float4 g4 = *(const float4*)(gamma + 4 * lane);
        float4 b4 = *(const float4*)(beta + 4 * lane);
#pragma unroll 2
        for (int j = 0; j < 32; j++) {
            int node = wid * 32 + j;
            int nid = s_nid13[node];
            int ll = s_leaf[2 * node], lr = s_leaf[2 * node + 1];
            float4 a = *(const float4*)(T0 + (long)nid * 256 + 4 * lane);
            float4 bb = *(const float4*)(T1 + (long)ll * 256 + 4 * lane);
            float4 cc = *(const float4*)(T2 + (long)lr * 256 + 4 * lane);
            float v0 = fmaxf(a.x + bb.x + cc.x + dd.x, 0.f);
            float v1 = fmaxf(a.y + bb.y + cc.y + dd.y, 0.f);
            float v2 = fmaxf(a.z + bb.z + cc.z + dd.z, 0.f);
            float v3 = fmaxf(a.w + bb.w + cc.w + dd.w, 0.f);
            float s = v0 + v1 + v2 + v3;
            float s2 = v0 * v0 + v1 * v1 + v2 * v2 + v3 * v3;
#pragma unroll
            for (int m = 1; m < 64; m <<= 1) {
                s += __shfl_xor(s, m);
                s2 += __shfl_xor(s2, m);
            }
            float mu = s * (1.f / 256.f);
            float rs = rsqrtf(s2 * (1.f / 256.f) - mu * mu + 1e-5f);
            ushort4 o;
            o.x = f2bf((v0 - mu) * rs * g4.x + b4.x);
            o.y = f2bf((v1 - mu) * rs * g4.y + b4.y);
            o.z = f2bf((v2 - mu) * rs * g4.z + b4.z);
            o.w = f2bf((v3 - mu) * rs * g4.w + b4.w);
            *(ushort4*)((char*)sA + node * 512 + ((8 * lane) ^ (((node >> 1) & 7) << 4))) = o;
        }
    }
    __syncthreads();

    f32x4 acc[4][4] = {};
    for (int kk = 0; kk < 16; kk++) {
        int k0 = kk * 32 + l4 * 8;
        int hi = k0 >> 8;
        int binr = (k0 & 255) * 2;
        bf16x8 af[4], bfr[4];
#pragma unroll
        for (int mi = 0; mi < 4; mi++) {
            int node = 2 * (mi * 16 + l15) + hi;
            af[mi] = *(const bf16x8*)((const char*)sA + node * 512 + (binr ^ (((node >> 1) & 7) << 4)));
        }
        const unsigned short* Wb = WTbf + (long)(256 + hi * 256) * 256;
        int innerk = k0 & 255;
#pragma unroll
        for (int ni = 0; ni < 4; ni++) {
            int cn = wid * 64 + ni * 16 + l15;
            bfr[ni] = *(const bf16x8*)(Wb + (long)cn * 256 + innerk);
        }
#pragma unroll
        for (int mi = 0; mi < 4; mi++)
#pragma unroll
            for (int ni = 0; ni < 4; ni++)
                acc[mi][ni] = __builtin_amdgcn_mfma_f32_16x16x32_bf16(af[mi], bfr[ni],
                                                                     acc[mi][ni], 0, 0, 0);
    }

    const float* carr_d = carr + 12 * 256;
    float cv[4], gv[4], bv[4];
#pragma unroll
    for (int ni = 0; ni < 4; ni++) {
        int c = wid * 64 + ni * 16 + l15;
        cv[ni] = carr_d[c];
        gv[ni] = gamma[c];
        bv[ni] = beta[c];
    }

#pragma unroll
    for (int mi = 0; mi < 4; mi++) {
#pragma unroll
        for (int r = 0; r < 4; r++) {
            int row = mi * 16 + l4 * 4 + r;
            int nid = s_nid[row];
            float s = 0.f, s2 = 0.f;
#pragma unroll
            for (int ni = 0; ni < 4; ni++) {
                int c = wid * 64 + ni * 16 + l15;
                float h = acc[mi][ni][r] + T0[(long)nid * 256 + c] + cv[ni];
                h = fmaxf(h, 0.f);
                acc[mi][ni][r] = h;
                s += h;
                s2 += h * h;
            }
#pragma unroll
            for (int m = 1; m < 16; m <<= 1) {
                s += __shfl_xor(s, m);
                s2 += __shfl_xor(s2, m);
            }
            if (l15 == 0) {
                s_part[wid][row][0] = s;
                s_part[wid][row][1] = s2;
            }
        }
    }
    __syncthreads();

#pragma unroll
    for (int mi = 0; mi < 4; mi++) {
#pragma unroll
        for (int r = 0; r < 4; r++) {
            int row = mi * 16 + l4 * 4 + r;
            float s = s_part[0][row][0] + s_part[1][row][0] + s_part[2][row][0] + s_part[3][row][0];
            float s2 = s_part[0][row][1] + s_part[1][row][1] + s_part[2][row][1] + s_part[3][row][1];
            float mu = s * (1.f / 256.f);
            float rs = rsqrtf(s2 * (1.f / 256.f) - mu * mu + 1e-5f);
            unsigned short* o = ebuf_out + ((long)b * 4096 + row0 + row) * 256;
#pragma unroll
            for (int ni = 0; ni < 4; ni++) {
                int c = wid * 64 + ni * 16 + l15;
                o[c] = f2bf((acc[mi][ni][r] - mu) * rs * gv[ni] + bv[ni]);
            }
        }
    }
}

// ---------------- Levels 11..8: MFMA GEMM + gather + relu + LN (MT*16 rows per block)
template <int MT>
__global__ __launch_bounds__(256) void k_level(const unsigned short* __restrict__ ebuf_prev,
                                               unsigned short* __restrict__ ebuf_out,
                                               const int* __restrict__ op_ids,
                                               const float* __restrict__ T0,
                                               const float* __restrict__ carr_d,
                                               const float* __restrict__ gamma,
                                               const float* __restrict__ beta,
                                               const unsigned short* __restrict__ WTbf,
                                               int n) {
    int wid = threadIdx.x >> 6, lane = threadIdx.x & 63;
    int b = blockIdx.y;
    int row0 = blockIdx.x * (MT * 16);
    int l15 = lane & 15, l4 = lane >> 4;

    __shared__ int s_nid[MT * 16];
    __shared__ float s_part[4][MT * 16][2];

    if (threadIdx.x < MT * 16)
        s_nid[threadIdx.x] = op_ids[b * 16383 + (n - 1) + row0 + threadIdx.x];
    __syncthreads();

    const unsigned short* X = ebuf_prev + (long)b * (2 * (long)n) * 256;

    f32x4 acc[MT][4] = {};

    for (int kk = 0; kk < 16; kk++) {
        int k0 = kk * 32 + l4 * 8;
        int hi = k0 >> 8;
        int innerk = k0 & 255;
        bf16x8 af[MT], bfr[4];
#pragma unroll
        for (int mi = 0; mi < MT; mi++) {
            int r = row0 + mi * 16 + l15;
            af[mi] = *(const bf16x8*)(X + (long)r * 512 + k0);
        }
        const unsigned short* Wb = WTbf + (long)(256 + hi * 256) * 256;
#pragma unroll
        for (int ni = 0; ni < 4; ni++) {
            int cn = wid * 64 + ni * 16 + l15;
            bfr[ni] = *(const bf16x8*)(Wb + (long)cn * 256 + innerk);
        }
#pragma unroll
        for (int mi = 0; mi < MT; mi++)
#pragma unroll
            for (int ni = 0; ni < 4; ni++)
                acc[mi][ni] = __builtin_amdgcn_mfma_f32_16x16x32_bf16(af[mi], bfr[ni],
                                                                     acc[mi][ni], 0, 0, 0);
    }

    float cv[4], gv[4], bv[4];
#pragma unroll
    for (int ni = 0; ni < 4; ni++) {
        int c = wid * 64 + ni * 16 + l15;
        cv[ni] = carr_d[c];
        gv[ni] = gamma[c];
        bv[ni] = beta[c];
    }

#pragma unroll
    for (int mi = 0; mi < MT; mi++) {
#pragma unroll
        for (int r = 0; r < 4; r++) {
            int row = mi * 16 + l4 * 4 + r;
            int nid = s_nid[row];
            float s = 0.f, s2 = 0.f;
#pragma unroll
            for (int ni = 0; ni < 4; ni++) {
                int c = wid * 64 + ni * 16 + l15;
                float h = acc[mi][ni][r] + T0[(long)nid * 256 + c] + cv[ni];
                h = fmaxf(h, 0.f);
                acc[mi][ni][r] = h;
                s += h;
                s2 += h * h;
            }
#pragma unroll
            for (int m = 1; m < 16; m <<= 1) {
                s += __shfl_xor(s, m);
                s2 += __shfl_xor(s2, m);
            }
            if (l15 == 0) {
                s_part[wid][row][0] = s;
                s_part[wid][row][1] = s2;
            }
        }
    }
    __syncthreads();

#pragma unroll
    for (int mi = 0; mi < MT; mi++) {
#pragma unroll
        for (int r = 0; r < 4; r++) {
            int row = mi * 16 + l4 * 4 + r;
            float s = s_part[0][row][0] + s_part[1][row][0] + s_part[2][row][0] + s_part[3][row][0];
            float s2 = s_part[0][row][1] + s_part[1][row][1] + s_part[2][row][1] + s_part[3][row][1];
            float mu = s * (1.f / 256.f);
            float rs = rsqrtf(s2 * (1.f / 256.f) - mu * mu + 1e-5f);
            unsigned short* o = ebuf_out + ((long)b * n + row0 + row) * 256;
#pragma unroll
            for (int ni = 0; ni < 4; ni++) {
                int c = wid * 64 + ni * 16 + l15;
                o[c] = f2bf((acc[mi][ni][r] - mu) * rs * gv[ni] + bv[ni]);
            }
        }
    }
}

// ---------------- Fused tail: levels 7..0, 8 blocks x 512 threads, B held in registers.
// __launch_bounds__(512,1): only 8 blocks exist -> 1 block/CU; VGPR cap 256 so breg
// (128 VGPRs) does NOT spill. (512,2) capped VGPR at 128 and spilled breg to scratch.
__global__ __launch_bounds__(512, 1) void k_tail(const unsigned short* __restrict__ prev,
                                                 const int* __restrict__ op_ids,
                                                 const float* __restrict__ T0,
                                                 const float* __restrict__ carr,
                                                 const float* __restrict__ gamma,
                                                 const float* __restrict__ beta,
                                                 const unsigned short* __restrict__ WTbf,
                                                 float* __restrict__ out) {
    __shared__ unsigned short sA[128 * 256];
    __shared__ unsigned short sB[64 * 256];
    __shared__ int s_nid_all[255];
    __shared__ float s_part[8][64][2];
    int b = blockIdx.x;
    int t = threadIdx.x;
    int wid = t >> 6, lane = t & 63;
    int l15 = lane & 15, l4 = lane >> 4;

    // B fragments for this wave's 32 cols, ALL 16 ksteps, held in registers across levels
    bf16x8 breg[16][2];
#pragma unroll
    for (int kk = 0; kk < 16; kk++) {
        int k0 = kk * 32 + l4 * 8;
        int hi = k0 >> 8;
        int innerk = k0 & 255;
        const unsigned short* Wb = WTbf + (long)(256 + hi * 256) * 256;
#pragma unroll
        for (int ni = 0; ni < 2; ni++) {
            int cn = wid * 32 + ni * 16 + l15;
            breg[kk][ni] = *(const bf16x8*)(Wb + (long)cn * 256 + innerk);
        }
    }

    if (t < 255) s_nid_all[t] = op_ids[b * 16383 + t];
    float gv[2], bv[2];
#pragma unroll
    for (int ni = 0; ni < 2; ni++) {
        int c = wid * 32 + ni * 16 + l15;
        gv[ni] = gamma[c];
        bv[ni] = beta[c];
    }
    __syncthreads();

    // ---- Level 7: GEMM from global X (256 rows/batch viewed as 128x512) -> sA (swizzled)
    {
        const unsigned short* X = prev + (long)b * 65536;  // 256*256
        const float* carr7 = carr + 7 * 256;
        float cv7[2];
#pragma unroll
        for (int ni = 0; ni < 2; ni++) cv7[ni] = carr7[wid * 32 + ni * 16 + l15];
#pragma unroll 1
        for (int h = 0; h < 2; h++) {
            // epilogue T0 prefetch for this half's 64 rows
            float tv[4][4][2];
#pragma unroll
            for (int mi = 0; mi < 4; mi++)
#pragma unroll
                for (int r = 0; r < 4; r++) {
                    int row = h * 64 + mi * 16 + l4 * 4 + r;
                    int nid = s_nid_all[127 + row];
#pragma unroll
                    for (int ni = 0; ni < 2; ni++)
                        tv[mi][r][ni] = T0[(long)nid * 256 + wid * 32 + ni * 16 + l15];
                }

            f32x4 acc[4][2] = {};
#pragma unroll
            for (int kk = 0; kk < 16; kk++) {
                int k0 = kk * 32 + l4 * 8;
                bf16x8 af[4];
#pragma unroll
                for (int mi = 0; mi < 4; mi++) {
                    int r = h * 64 + mi * 16 + l15;
                    af[mi] = *(const bf16x8*)(X + (long)r * 512 + k0);
                }
#pragma unroll
                for (int mi = 0; mi < 4; mi++)
#pragma unroll
                    for (int ni = 0; ni < 2; ni++)
                        acc[mi][ni] = __builtin_amdgcn_mfma_f32_16x16x32_bf16(af[mi], breg[kk][ni],
                                                                             acc[mi][ni], 0, 0, 0);
            }

#pragma unroll
            for (int mi = 0; mi < 4; mi++)
#pragma unroll
                for (int r = 0; r < 4; r++) {
                    float s = 0.f, s2 = 0.f;
#pragma unroll
                    for (int ni = 0; ni < 2; ni++) {
                        float hh = acc[mi][ni][r] + tv[mi][r][ni] + cv7[ni];
                        hh = fmaxf(hh, 0.f);
                        acc[mi][ni][r] = hh;
                        s += hh;
                        s2 += hh * hh;
                    }
#pragma unroll
                    for (int m = 1; m < 16; m <<= 1) {
                        s += __shfl_xor(s, m);
                        s2 += __shfl_xor(s2, m);
                    }
                    if (l15 == 0) {
                        int row = mi * 16 + l4 * 4 + r;
                        s_part[wid][row][0] = s;
                        s_part[wid][row][1] = s2;
                    }
                }
            __syncthreads();

#pragma unroll
            for (int mi = 0; mi < 4; mi++)
#pragma unroll
                for (int r = 0; r < 4; r++) {
                    int row = mi * 16 + l4 * 4 + r;
                    float s = 0.f, s2 = 0.f;
#pragma unroll
                    for (int w = 0; w < 8; w++) {
                        s += s_part[w][row][0];
                        s2 += s_part[w][row][1];
                    }
                    float mu = s * (1.f / 256.f);
                    float rs = rsqrtf(s2 * (1.f / 256.f) - mu * mu + 1e-5f);
                    int rowL = h * 64 + row;
#pragma unroll
                    for (int ni = 0; ni < 2; ni++) {
                        int c = wid * 32 + ni * 16 + l15;
                        unsigned short val = f2bf((acc[mi][ni][r] - mu) * rs * gv[ni] + bv[ni]);
                        *(unsigned short*)((char*)sA + rowL * 512 +
                                           ((c * 2) ^ (((rowL >> 1) & 7) << 4))) = val;
                    }
                }
            __syncthreads();
        }
    }

    // ---- Levels 6..0, LDS ping-pong
    unsigned short* cur = sA;
    unsigned short* nxt = sB;
    for (int ld = 6; ld >= 0; ld--) {
        int n = 1 << ld;
        int mtiles = (n + 15) >> 4;

        // prefetch epilogue T0 values (independent of level chain)
        float tv[4][4][2];
#pragma unroll
        for (int mi = 0; mi < 4; mi++)
            if (mi < mtiles)
#pragma unroll
                for (int r = 0; r < 4; r++) {
                    int row = mi * 16 + l4 * 4 + r;
                    int rc = row < n ? row : n - 1;
                    int nid = s_nid_all[(n - 1) + rc];
#pragma unroll
                    for (int ni = 0; ni < 2; ni++)
                        tv[mi][r][ni] = T0[(long)nid * 256 + wid * 32 + ni * 16 + l15];
                }

        f32x4 acc[4][2] = {};
#pragma unroll
        for (int kk = 0; kk < 16; kk++) {
            int k0 = kk * 32 + l4 * 8;
            int hi = k0 >> 8;
            int binr = (k0 & 255) * 2;
            bf16x8 af[4];
#pragma unroll
            for (int mi = 0; mi < 4; mi++)
                if (mi < mtiles) {
                    int node = 2 * (mi * 16 + l15) + hi;
                    af[mi] = *(const bf16x8*)((const char*)cur + node * 512 +
                                              (binr ^ (((node >> 1) & 7) << 4)));
                }
#pragma unroll
            for (int mi = 0; mi < 4; mi++)
                if (mi < mtiles)
#pragma unroll
                    for (int ni = 0; ni < 2; ni++)
                        acc[mi][ni] = __builtin_amdgcn_mfma_f32_16x16x32_bf16(af[mi], breg[kk][ni],
                                                                             acc[mi][ni], 0, 0, 0);
        }

        const float* carr_d = carr + ld * 256;
        float cv[2];
#pragma unroll
        for (int ni = 0; ni < 2; ni++) cv[ni] = carr_d[wid * 32 + ni * 16 + l15];

#pragma unroll
        for (int mi = 0; mi < 4; mi++)
            if (mi < mtiles)
#pragma unroll
                for (int r = 0; r < 4; r++) {
                    float s = 0.f, s2 = 0.f;
#pragma unroll
                    for (int ni = 0; ni < 2; ni++) {
                        float h = acc[mi][ni][r] + tv[mi][r][ni] + cv[ni];
                        h = fmaxf(h, 0.f);
                        acc[mi][ni][r] = h;
                        s += h;
                        s2 += h * h;
                    }
#pragma unroll
                    for (int m = 1; m < 16; m <<= 1) {
                        s += __shfl_xor(s, m);
                        s2 += __shfl_xor(s2, m);
                    }
                    if (l15 == 0) {
                        int row = mi * 16 + l4 * 4 + r;
                        s_part[wid][row][0] = s;
                        s_part[wid][row][1] = s2;
                    }
                }
        __syncthreads();

#pragma unroll
        for (int mi = 0; mi < 4; mi++)
            if (mi < mtiles)
#pragma unroll
                for (int r = 0; r < 4; r++) {
                    int row = mi * 16 + l4 * 4 + r;
                    if (row < n) {
                        float s = 0.f, s2 = 0.f;
#pragma unroll
                        for (int w = 0; w < 8; w++) {
                            s += s_part[w][row][0];
                            s2 += s_part[w][row][1];
                        }
                        float mu = s * (1.f / 256.f);
                        float rs = rsqrtf(s2 * (1.f / 256.f) - mu * mu + 1e-5f);
                        if (ld == 0) {
                            if (row == 0) {
#pragma unroll
                                for (int ni = 0; ni < 2; ni++) {
                                    int c = wid * 32 + ni * 16 + l15;
                                    out[b * 256 + c] = (acc[mi][ni][r] - mu) * rs * gv[ni] + bv[ni];
                                }
                            }
                        } else {
#pragma unroll
                            for (int ni = 0; ni < 2; ni++) {
                                int c = wid * 32 + ni * 16 + l15;
                                unsigned short val = f2bf((acc[mi][ni][r] - mu) * rs * gv[ni] + bv[ni]);
                                *(unsigned short*)((char*)nxt + row * 512 +
                                                   ((c * 2) ^ (((row >> 1) & 7) << 4))) = val;
                            }
                        }
                    }
                }
        __syncthreads();
        unsigned short* tmp = cur;
        cur = nxt;
        nxt = tmp;
    }
}

extern "C" void kernel_launch(void* const* d_in, const int* in_sizes, int n_in,
                              void* d_out, int out_size, void* d_ws, size_t ws_size,
                              hipStream_t stream) {
    const int* leaf_ids = (const int*)d_in[0];
    const int* op_ids = (const int*)d_in[1];
    const float* tok = (const float*)d_in[2];
    const float* dep = (const float*)d_in[3];
    const float* idx = (const float*)d_in[4];
    const float* W = (const float*)d_in[5];
    const float* bvec = (const float*)d_in[6];
    const float* gamma = (const float*)d_in[7];
    const float* beta = (const float*)d_in[8];
    float* out = (float*)d_out;

    char* ws = (char*)d_ws;
    float* T = (float*)(ws);                                             // 3 MB (T0|T1|T2)
    unsigned short* WTbf = (unsigned short*)(ws + 3u * 1024 * 1024);     // 384 KB
    unsigned short* tokbf = (unsigned short*)(ws + 3u * 1024 * 1024 + 512 * 1024);  // 512 KB
    float* carr = (float*)(ws + 4u * 1024 * 1024 + 64 * 1024);           // 14 KB
    unsigned short* ebufA = (unsigned short*)(ws + 8u * 1024 * 1024);    // 16 MB
    unsigned short* ebufB = (unsigned short*)(ws + 40u * 1024 * 1024);   // 8 MB

    k_prep<<<318, 256, 0, stream>>>(tok, W, dep, idx, bvec, tokbf, WTbf, carr);
    k_ttmm<<<dim3(32, 3), 256, 0, stream>>>(tokbf, WTbf, T);

    // levels 13+12 -> ebufA (4096 rows/batch)
    k_level12f<<<dim3(64, 8), 256, 0, stream>>>(leaf_ids, op_ids, T, carr, gamma, beta, WTbf,
                                                ebufA);
    // level 11 -> ebufB (2048 rows/batch)
    k_level<4><<<dim3(32, 8), 256, 0, stream>>>(ebufA, ebufB, op_ids, T, carr + 11 * 256, gamma,
                                                beta, WTbf, 2048);
    // level 10 -> ebufA (1024 rows/batch)
    k_level<2><<<dim3(32, 8), 256, 0, stream>>>(ebufB, ebufA, op_ids, T, carr + 10 * 256, gamma,
                                                beta, WTbf, 1024);
    // level 9 -> ebufB (512 rows/batch)
    k_level<2><<<dim3(16, 8), 256, 0, stream>>>(ebufA, ebufB, op_ids, T, carr + 9 * 256, gamma,
                                                beta, WTbf, 512);
    // level 8 -> ebufA (256 rows/batch)
    k_level<2><<<dim3(8, 8), 256, 0, stream>>>(ebufB, ebufA, op_ids, T, carr + 8 * 256, gamma,
                                               beta, WTbf, 256);
    // levels 7..0
    k_tail<<<8, 512, 0, stream>>>(ebufA, op_ids, T, carr, gamma, beta, WTbf, out);
}

// Round 8
// 341.326 us; speedup vs baseline: 1.0518x; 1.0518x over previous
//
#include <hip/hip_runtime.h>

typedef float f32x4 __attribute__((ext_vector_type(4)));
typedef short bf16x8 __attribute__((ext_vector_type(8)));

__device__ inline unsigned short f2bf(float f) {
    unsigned int u = __builtin_bit_cast(unsigned int, f);
    unsigned int r = (u + 0x7FFFu + ((u >> 16) & 1u)) >> 16;
    return (unsigned short)r;
}

// ---------------- Combined prep: tok->bf16 | W transpose->bf16 | carr vectors
__global__ __launch_bounds__(256) void k_prep(const float* __restrict__ tok,
                                              const float* __restrict__ W,
                                              const float* __restrict__ dep,
                                              const float* __restrict__ idx,
                                              const float* __restrict__ bvec,
                                              unsigned short* __restrict__ tokbf,
                                              unsigned short* __restrict__ WTbf,
                                              float* __restrict__ carr) {
    __shared__ float s_tile[64][65];
    int bx = blockIdx.x;
    if (bx < 256) {
        int i = bx * 256 + threadIdx.x;
        const float4 v = *(const float4*)(tok + (long)i * 4);
        ushort4 o;
        o.x = f2bf(v.x); o.y = f2bf(v.y); o.z = f2bf(v.z); o.w = f2bf(v.w);
        *(ushort4*)(tokbf + (long)i * 4) = o;
    } else if (bx < 304) {
        int bb = bx - 256;
        int sec = bb >> 4;
        int tt = bb & 15;
        int k0 = (tt >> 2) * 64, j0 = (tt & 3) * 64;
        int tx = threadIdx.x & 63, ty = threadIdx.x >> 6;
#pragma unroll
        for (int r = 0; r < 16; r++) {
            int kk = ty * 16 + r;
            s_tile[kk][tx] = W[(sec * 256 + k0 + kk) * 256 + j0 + tx];
        }
        __syncthreads();
#pragma unroll
        for (int r = 0; r < 16; r++) {
            int jj = ty * 16 + r;
            WTbf[(sec * 256 + j0 + jj) * 256 + k0 + tx] = f2bf(s_tile[tx][jj]);
        }
    } else {
        int d = bx - 304;
        int j = threadIdx.x;
        float acc = bvec[j];
#pragma unroll 4
        for (int k = 0; k < 256; k++) {
            float dv = dep[(d + 1) * 256 + k];
            acc += dv * (W[(768 + k) * 256 + j] + W[(1280 + k) * 256 + j]);
            acc += idx[k] * W[(1024 + k) * 256 + j];
            acc += idx[256 + k] * W[(1536 + k) * 256 + j];
        }
        if (d == 13) {
#pragma unroll 4
            for (int k = 0; k < 256; k++) {
                float dv = dep[14 * 256 + k];
                acc += dv * (W[(256 + k) * 256 + j] + W[(512 + k) * 256 + j]);
            }
        }
        carr[d * 256 + j] = acc;
    }
}

// ---------------- T tables via MFMA: T[sec][1024][256] = tokbf @ Wsec
__global__ __launch_bounds__(256) void k_ttmm(const unsigned short* __restrict__ tokbf,
                                              const unsigned short* __restrict__ WTbf,
                                              float* __restrict__ T) {
    int wid = threadIdx.x >> 6, lane = threadIdx.x & 63;
    int l15 = lane & 15, l4 = lane >> 4;
    int row0 = blockIdx.x * 32;
    int sec = blockIdx.y;

    f32x4 acc[2][4] = {};
    for (int kk = 0; kk < 8; kk++) {
        int k0 = kk * 32 + l4 * 8;
        bf16x8 af[2], bfr[4];
#pragma unroll
        for (int mi = 0; mi < 2; mi++)
            af[mi] = *(const bf16x8*)(tokbf + (long)(row0 + mi * 16 + l15) * 256 + k0);
#pragma unroll
        for (int ni = 0; ni < 4; ni++)
            bfr[ni] = *(const bf16x8*)(WTbf + (long)(sec * 256 + wid * 64 + ni * 16 + l15) * 256 + k0);
#pragma unroll
        for (int mi = 0; mi < 2; mi++)
#pragma unroll
            for (int ni = 0; ni < 4; ni++)
                acc[mi][ni] = __builtin_amdgcn_mfma_f32_16x16x32_bf16(af[mi], bfr[ni],
                                                                     acc[mi][ni], 0, 0, 0);
    }
#pragma unroll
    for (int mi = 0; mi < 2; mi++)
#pragma unroll
        for (int r = 0; r < 4; r++) {
            int row = row0 + mi * 16 + l4 * 4 + r;
#pragma unroll
            for (int ni = 0; ni < 4; ni++) {
                int c = wid * 64 + ni * 16 + l15;
                T[(long)sec * 262144 + (long)row * 256 + c] = acc[mi][ni][r];
            }
        }
}

// ---------------- Fused level 13+12
__global__ __launch_bounds__(256) void k_level12f(const int* __restrict__ leaf_ids,
                                                  const int* __restrict__ op_ids,
                                                  const float* __restrict__ T,
                                                  const float* __restrict__ carr,
                                                  const float* __restrict__ gamma,
                                                  const float* __restrict__ beta,
                                                  const unsigned short* __restrict__ WTbf,
                                                  unsigned short* __restrict__ ebuf_out) {
    __shared__ unsigned short sA[128 * 256];
    __shared__ int s_nid13[128];
    __shared__ int s_leaf[256];
    __shared__ int s_nid[64];
    __shared__ float s_part[4][64][2];
    int b = blockIdx.y;
    int row0 = blockIdx.x * 64;
    int t = threadIdx.x;
    int wid = t >> 6, lane = t & 63;
    int l15 = lane & 15, l4 = lane >> 4;
    const float* T0 = T;
    const float* T1 = T + 262144;
    const float* T2 = T + 524288;

    if (t < 128) s_nid13[t] = op_ids[b * 16383 + 8191 + 2 * row0 + t];
    s_leaf[t] = leaf_ids[b * 16384 + 4 * row0 + t];
    if (t < 64) s_nid[t] = op_ids[b * 16383 + 4095 + row0 + t];
    __syncthreads();

    {
        const float* c13 = carr + 13 * 256;
        float4 dd = *(const float4*)(c13 + 4 * lane);
        float4 g4 = *(const float4*)(gamma + 4 * lane);
        float4 b4 = *(const float4*)(beta + 4 * lane);
#pragma unroll 2
        for (int j = 0; j < 32; j++) {
            int node = wid * 32 + j;
            int nid = s_nid13[node];
            int ll = s_leaf[2 * node], lr = s_leaf[2 * node + 1];
            float4 a = *(const float4*)(T0 + (long)nid * 256 + 4 * lane);
            float4 bb = *(const float4*)(T1 + (long)ll * 256 + 4 * lane);
            float4 cc = *(const float4*)(T2 + (long)lr * 256 + 4 * lane);
            float v0 = fmaxf(a.x + bb.x + cc.x + dd.x, 0.f);
            float v1 = fmaxf(a.y + bb.y + cc.y + dd.y, 0.f);
            float v2 = fmaxf(a.z + bb.z + cc.z + dd.z, 0.f);
            float v3 = fmaxf(a.w + bb.w + cc.w + dd.w, 0.f);
            float s = v0 + v1 + v2 + v3;
            float s2 = v0 * v0 + v1 * v1 + v2 * v2 + v3 * v3;
#pragma unroll
            for (int m = 1; m < 64; m <<= 1) {
                s += __shfl_xor(s, m);
                s2 += __shfl_xor(s2, m);
            }
            float mu = s * (1.f / 256.f);
            float rs = rsqrtf(s2 * (1.f / 256.f) - mu * mu + 1e-5f);
            ushort4 o;
            o.x = f2bf((v0 - mu) * rs * g4.x + b4.x);
            o.y = f2bf((v1 - mu) * rs * g4.y + b4.y);
            o.z = f2bf((v2 - mu) * rs * g4.z + b4.z);
            o.w = f2bf((v3 - mu) * rs * g4.w + b4.w);
            *(ushort4*)((char*)sA + node * 512 + ((8 * lane) ^ (((node >> 1) & 7) << 4))) = o;
        }
    }
    __syncthreads();

    f32x4 acc[4][4] = {};
    for (int kk = 0; kk < 16; kk++) {
        int k0 = kk * 32 + l4 * 8;
        int hi = k0 >> 8;
        int binr = (k0 & 255) * 2;
        bf16x8 af[4], bfr[4];
#pragma unroll
        for (int mi = 0; mi < 4; mi++) {
            int node = 2 * (mi * 16 + l15) + hi;
            af[mi] = *(const bf16x8*)((const char*)sA + node * 512 + (binr ^ (((node >> 1) & 7) << 4)));
        }
        const unsigned short* Wb = WTbf + (long)(256 + hi * 256) * 256;
        int innerk = k0 & 255;
#pragma unroll
        for (int ni = 0; ni < 4; ni++) {
            int cn = wid * 64 + ni * 16 + l15;
            bfr[ni] = *(const bf16x8*)(Wb + (long)cn * 256 + innerk);
        }
#pragma unroll
        for (int mi = 0; mi < 4; mi++)
#pragma unroll
            for (int ni = 0; ni < 4; ni++)
                acc[mi][ni] = __builtin_amdgcn_mfma_f32_16x16x32_bf16(af[mi], bfr[ni],
                                                                     acc[mi][ni], 0, 0, 0);
    }

    const float* carr_d = carr + 12 * 256;
    float cv[4], gv[4], bv[4];
#pragma unroll
    for (int ni = 0; ni < 4; ni++) {
        int c = wid * 64 + ni * 16 + l15;
        cv[ni] = carr_d[c];
        gv[ni] = gamma[c];
        bv[ni] = beta[c];
    }

#pragma unroll
    for (int mi = 0; mi < 4; mi++) {
#pragma unroll
        for (int r = 0; r < 4; r++) {
            int row = mi * 16 + l4 * 4 + r;
            int nid = s_nid[row];
            float s = 0.f, s2 = 0.f;
#pragma unroll
            for (int ni = 0; ni < 4; ni++) {
                int c = wid * 64 + ni * 16 + l15;
                float h = acc[mi][ni][r] + T0[(long)nid * 256 + c] + cv[ni];
                h = fmaxf(h, 0.f);
                acc[mi][ni][r] = h;
                s += h;
                s2 += h * h;
            }
#pragma unroll
            for (int m = 1; m < 16; m <<= 1) {
                s += __shfl_xor(s, m);
                s2 += __shfl_xor(s2, m);
            }
            if (l15 == 0) {
                s_part[wid][row][0] = s;
                s_part[wid][row][1] = s2;
            }
        }
    }
    __syncthreads();

#pragma unroll
    for (int mi = 0; mi < 4; mi++) {
#pragma unroll
        for (int r = 0; r < 4; r++) {
            int row = mi * 16 + l4 * 4 + r;
            float s = s_part[0][row][0] + s_part[1][row][0] + s_part[2][row][0] + s_part[3][row][0];
            float s2 = s_part[0][row][1] + s_part[1][row][1] + s_part[2][row][1] + s_part[3][row][1];
            float mu = s * (1.f / 256.f);
            float rs = rsqrtf(s2 * (1.f / 256.f) - mu * mu + 1e-5f);
            unsigned short* o = ebuf_out + ((long)b * 4096 + row0 + row) * 256;
#pragma unroll
            for (int ni = 0; ni < 4; ni++) {
                int c = wid * 64 + ni * 16 + l15;
                o[c] = f2bf((acc[mi][ni][r] - mu) * rs * gv[ni] + bv[ni]);
            }
        }
    }
}

// ---------------- Levels 11..8: MFMA GEMM + gather + relu + LN (MT*16 rows per block)
template <int MT>
__global__ __launch_bounds__(256) void k_level(const unsigned short* __restrict__ ebuf_prev,
                                               unsigned short* __restrict__ ebuf_out,
                                               const int* __restrict__ op_ids,
                                               const float* __restrict__ T0,
                                               const float* __restrict__ carr_d,
                                               const float* __restrict__ gamma,
                                               const float* __restrict__ beta,
                                               const unsigned short* __restrict__ WTbf,
                                               int n) {
    int wid = threadIdx.x >> 6, lane = threadIdx.x & 63;
    int b = blockIdx.y;
    int row0 = blockIdx.x * (MT * 16);
    int l15 = lane & 15, l4 = lane >> 4;

    __shared__ int s_nid[MT * 16];
    __shared__ float s_part[4][MT * 16][2];

    if (threadIdx.x < MT * 16)
        s_nid[threadIdx.x] = op_ids[b * 16383 + (n - 1) + row0 + threadIdx.x];
    __syncthreads();

    const unsigned short* X = ebuf_prev + (long)b * (2 * (long)n) * 256;

    f32x4 acc[MT][4] = {};

    for (int kk = 0; kk < 16; kk++) {
        int k0 = kk * 32 + l4 * 8;
        int hi = k0 >> 8;
        int innerk = k0 & 255;
        bf16x8 af[MT], bfr[4];
#pragma unroll
        for (int mi = 0; mi < MT; mi++) {
            int r = row0 + mi * 16 + l15;
            af[mi] = *(const bf16x8*)(X + (long)r * 512 + k0);
        }
        const unsigned short* Wb = WTbf + (long)(256 + hi * 256) * 256;
#pragma unroll
        for (int ni = 0; ni < 4; ni++) {
            int cn = wid * 64 + ni * 16 + l15;
            bfr[ni] = *(const bf16x8*)(Wb + (long)cn * 256 + innerk);
        }
#pragma unroll
        for (int mi = 0; mi < MT; mi++)
#pragma unroll
            for (int ni = 0; ni < 4; ni++)
                acc[mi][ni] = __builtin_amdgcn_mfma_f32_16x16x32_bf16(af[mi], bfr[ni],
                                                                     acc[mi][ni], 0, 0, 0);
    }

    float cv[4], gv[4], bv[4];
#pragma unroll
    for (int ni = 0; ni < 4; ni++) {
        int c = wid * 64 + ni * 16 + l15;
        cv[ni] = carr_d[c];
        gv[ni] = gamma[c];
        bv[ni] = beta[c];
    }

#pragma unroll
    for (int mi = 0; mi < MT; mi++) {
#pragma unroll
        for (int r = 0; r < 4; r++) {
            int row = mi * 16 + l4 * 4 + r;
            int nid = s_nid[row];
            float s = 0.f, s2 = 0.f;
#pragma unroll
            for (int ni = 0; ni < 4; ni++) {
                int c = wid * 64 + ni * 16 + l15;
                float h = acc[mi][ni][r] + T0[(long)nid * 256 + c] + cv[ni];
                h = fmaxf(h, 0.f);
                acc[mi][ni][r] = h;
                s += h;
                s2 += h * h;
            }
#pragma unroll
            for (int m = 1; m < 16; m <<= 1) {
                s += __shfl_xor(s, m);
                s2 += __shfl_xor(s2, m);
            }
            if (l15 == 0) {
                s_part[wid][row][0] = s;
                s_part[wid][row][1] = s2;
            }
        }
    }
    __syncthreads();

#pragma unroll
    for (int mi = 0; mi < MT; mi++) {
#pragma unroll
        for (int r = 0; r < 4; r++) {
            int row = mi * 16 + l4 * 4 + r;
            float s = s_part[0][row][0] + s_part[1][row][0] + s_part[2][row][0] + s_part[3][row][0];
            float s2 = s_part[0][row][1] + s_part[1][row][1] + s_part[2][row][1] + s_part[3][row][1];
            float mu = s * (1.f / 256.f);
            float rs = rsqrtf(s2 * (1.f / 256.f) - mu * mu + 1e-5f);
            unsigned short* o = ebuf_out + ((long)b * n + row0 + row) * 256;
#pragma unroll
            for (int ni = 0; ni < 4; ni++) {
                int c = wid * 64 + ni * 16 + l15;
                o[c] = f2bf((acc[mi][ni][r] - mu) * rs * gv[ni] + bv[ni]);
            }
        }
    }
}

// ---------------- Subtree tail: levels 7..1. 16 blocks (block = (batch, half)), 512 threads,
// 8 waves x 32 cols (R6's passing wave decomposition; per-level global Wb loads, no breg).
// Level-1 embedding written to mid (bf16). Level 0 in k_root.
__global__ __launch_bounds__(512) void k_tail(const unsigned short* __restrict__ prev,
                                              const int* __restrict__ op_ids,
                                              const float* __restrict__ T0,
                                              const float* __restrict__ carr,
                                              const float* __restrict__ gamma,
                                              const float* __restrict__ beta,
                                              const unsigned short* __restrict__ WTbf,
                                              unsigned short* __restrict__ mid) {
    __shared__ unsigned short sA[64 * 256];
    __shared__ unsigned short sB[64 * 256];
    __shared__ int s_nid_all[255];
    __shared__ float s_part[8][64][2];
    int b = blockIdx.x >> 1;
    int h = blockIdx.x & 1;
    int t = threadIdx.x;
    int wid = t >> 6, lane = t & 63;
    int l15 = lane & 15, l4 = lane >> 4;

    if (t < 255) s_nid_all[t] = op_ids[b * 16383 + t];
    float gv[2], bv[2];
#pragma unroll
    for (int ni = 0; ni < 2; ni++) {
        int c = wid * 32 + ni * 16 + l15;
        gv[ni] = gamma[c];
        bv[ni] = beta[c];
    }
    __syncthreads();

    unsigned short* cur = sA;
    unsigned short* nxt = sB;

    // ---- Level 7: 64 local rows (global level-7 nodes h*64 + [0,64)) from global X -> sA
    {
        const unsigned short* X = prev + ((long)b * 256 + h * 128) * 256;
        const float* carr7 = carr + 7 * 256;
        float cv7[2];
#pragma unroll
        for (int ni = 0; ni < 2; ni++) cv7[ni] = carr7[wid * 32 + ni * 16 + l15];

        float tv[4][4][2];
#pragma unroll
        for (int mi = 0; mi < 4; mi++)
#pragma unroll
            for (int r = 0; r < 4; r++) {
                int row = mi * 16 + l4 * 4 + r;
                int nid = s_nid_all[127 + h * 64 + row];
#pragma unroll
                for (int ni = 0; ni < 2; ni++)
                    tv[mi][r][ni] = T0[(long)nid * 256 + wid * 32 + ni * 16 + l15];
            }

        f32x4 acc[4][2] = {};
        for (int kk = 0; kk < 16; kk++) {
            int k0 = kk * 32 + l4 * 8;
            int hi = k0 >> 8;
            int innerk = k0 & 255;
            bf16x8 af[4], bfr[2];
#pragma unroll
            for (int mi = 0; mi < 4; mi++)
                af[mi] = *(const bf16x8*)(X + (long)(mi * 16 + l15) * 512 + k0);
            const unsigned short* Wb = WTbf + (long)(256 + hi * 256) * 256;
#pragma unroll
            for (int ni = 0; ni < 2; ni++) {
                int cn = wid * 32 + ni * 16 + l15;
                bfr[ni] = *(const bf16x8*)(Wb + (long)cn * 256 + innerk);
            }
#pragma unroll
            for (int mi = 0; mi < 4; mi++)
#pragma unroll
                for (int ni = 0; ni < 2; ni++)
                    acc[mi][ni] = __builtin_amdgcn_mfma_f32_16x16x32_bf16(af[mi], bfr[ni],
                                                                         acc[mi][ni], 0, 0, 0);
        }

#pragma unroll
        for (int mi = 0; mi < 4; mi++)
#pragma unroll
            for (int r = 0; r < 4; r++) {
                float s = 0.f, s2 = 0.f;
#pragma unroll
                for (int ni = 0; ni < 2; ni++) {
                    float hh = fmaxf(acc[mi][ni][r] + tv[mi][r][ni] + cv7[ni], 0.f);
                    acc[mi][ni][r] = hh;
                    s += hh;
                    s2 += hh * hh;
                }
#pragma unroll
                for (int m = 1; m < 16; m <<= 1) {
                    s += __shfl_xor(s, m);
                    s2 += __shfl_xor(s2, m);
                }
                if (l15 == 0) {
                    int row = mi * 16 + l4 * 4 + r;
                    s_part[wid][row][0] = s;
                    s_part[wid][row][1] = s2;
                }
            }
        __syncthreads();

#pragma unroll
        for (int mi = 0; mi < 4; mi++)
#pragma unroll
            for (int r = 0; r < 4; r++) {
                int row = mi * 16 + l4 * 4 + r;
                float s = 0.f, s2 = 0.f;
#pragma unroll
                for (int w = 0; w < 8; w++) {
                    s += s_part[w][row][0];
                    s2 += s_part[w][row][1];
                }
                float mu = s * (1.f / 256.f);
                float rs = rsqrtf(s2 * (1.f / 256.f) - mu * mu + 1e-5f);
#pragma unroll
                for (int ni = 0; ni < 2; ni++) {
                    int c = wid * 32 + ni * 16 + l15;
                    unsigned short val = f2bf((acc[mi][ni][r] - mu) * rs * gv[ni] + bv[ni]);
                    *(unsigned short*)((char*)sA + row * 512 +
                                       ((c * 2) ^ (((row >> 1) & 7) << 4))) = val;
                }
            }
        __syncthreads();
    }

    // ---- Levels 6..1: m = 2^(ld-1) local rows; LDS ping-pong; ld==1 writes mid
    for (int ld = 6; ld >= 1; ld--) {
        int ng = 1 << ld;   // global nodes at this level
        int m = ng >> 1;    // local rows (this subtree half)
        int mtiles = (m + 15) >> 4;

        float tv[2][4][2];
#pragma unroll
        for (int mi = 0; mi < 2; mi++)
            if (mi < mtiles)
#pragma unroll
                for (int r = 0; r < 4; r++) {
                    int row = mi * 16 + l4 * 4 + r;
                    int rc = row < m ? row : m - 1;
                    int nid = s_nid_all[(ng - 1) + h * m + rc];
#pragma unroll
                    for (int ni = 0; ni < 2; ni++)
                        tv[mi][r][ni] = T0[(long)nid * 256 + wid * 32 + ni * 16 + l15];
                }

        f32x4 acc[2][2] = {};
        for (int kk = 0; kk < 16; kk++) {
            int k0 = kk * 32 + l4 * 8;
            int hi = k0 >> 8;
            int innerk = k0 & 255;
            int binr = innerk * 2;
            bf16x8 af[2], bfr[2];
#pragma unroll
            for (int mi = 0; mi < 2; mi++)
                if (mi < mtiles) {
                    int node = 2 * (mi * 16 + l15) + hi;
                    af[mi] = *(const bf16x8*)((const char*)cur + node * 512 +
                                              (binr ^ (((node >> 1) & 7) << 4)));
                }
            const unsigned short* Wb = WTbf + (long)(256 + hi * 256) * 256;
#pragma unroll
            for (int ni = 0; ni < 2; ni++) {
                int cn = wid * 32 + ni * 16 + l15;
                bfr[ni] = *(const bf16x8*)(Wb + (long)cn * 256 + innerk);
            }
#pragma unroll
            for (int mi = 0; mi < 2; mi++)
                if (mi < mtiles)
#pragma unroll
                    for (int ni = 0; ni < 2; ni++)
                        acc[mi][ni] = __builtin_amdgcn_mfma_f32_16x16x32_bf16(af[mi], bfr[ni],
                                                                             acc[mi][ni], 0, 0, 0);
        }

        const float* carr_d = carr + ld * 256;
        float cv[2];
#pragma unroll
        for (int ni = 0; ni < 2; ni++) cv[ni] = carr_d[wid * 32 + ni * 16 + l15];

#pragma unroll
        for (int mi = 0; mi < 2; mi++)
            if (mi < mtiles)
#pragma unroll
                for (int r = 0; r < 4; r++) {
                    float s = 0.f, s2 = 0.f;
#pragma unroll
                    for (int ni = 0; ni < 2; ni++) {
                        float hh = fmaxf(acc[mi][ni][r] + tv[mi][r][ni] + cv[ni], 0.f);
                        acc[mi][ni][r] = hh;
                        s += hh;
                        s2 += hh * hh;
                    }
#pragma unroll
                    for (int m2 = 1; m2 < 16; m2 <<= 1) {
                        s += __shfl_xor(s, m2);
                        s2 += __shfl_xor(s2, m2);
                    }
                    if (l15 == 0) {
                        int row = mi * 16 + l4 * 4 + r;
                        s_part[wid][row][0] = s;
                        s_part[wid][row][1] = s2;
                    }
                }
        __syncthreads();

#pragma unroll
        for (int mi = 0; mi < 2; mi++)
            if (mi < mtiles)
#pragma unroll
                for (int r = 0; r < 4; r++) {
                    int row = mi * 16 + l4 * 4 + r;
                    if (row < m) {
                        float s = 0.f, s2 = 0.f;
#pragma unroll
                        for (int w = 0; w < 8; w++) {
                            s += s_part[w][row][0];
                            s2 += s_part[w][row][1];
                        }
                        float mu = s * (1.f / 256.f);
                        float rs = rsqrtf(s2 * (1.f / 256.f) - mu * mu + 1e-5f);
#pragma unroll
                        for (int ni = 0; ni < 2; ni++) {
                            int c = wid * 32 + ni * 16 + l15;
                            float val = (acc[mi][ni][r] - mu) * rs * gv[ni] + bv[ni];
                            if (ld == 1) {
                                mid[(long)(b * 2 + h) * 256 + c] = f2bf(val);
                            } else {
                                *(unsigned short*)((char*)nxt + row * 512 +
                                                   ((c * 2) ^ (((row >> 1) & 7) << 4))) = f2bf(val);
                            }
                        }
                    }
                }
        __syncthreads();
        unsigned short* tmp = cur;
        cur = nxt;
        nxt = tmp;
    }
}

// ---------------- Root (level 0): one block, 4 waves. GEMM 8 rows (batches) x K=512 x N=256.
__global__ __launch_bounds__(256) void k_root(const unsigned short* __restrict__ mid,
                                              const int* __restrict__ op_ids,
                                              const float* __restrict__ T0,
                                              const float* __restrict__ carr,
                                              const float* __restrict__ gamma,
                                              const float* __restrict__ beta,
                                              const unsigned short* __restrict__ WTbf,
                                              float* __restrict__ out) {
    __shared__ float s_part[4][16][2];
    int t = threadIdx.x;
    int wid = t >> 6, lane = t & 63;
    int l15 = lane & 15, l4 = lane >> 4;

    f32x4 acc[4] = {};
    for (int kk = 0; kk < 16; kk++) {
        int k0 = kk * 32 + l4 * 8;
        int hi = k0 >> 8;
        int innerk = k0 & 255;
        int arow = l15 & 7;  // rows 8..15 mirror 0..7; their outputs are discarded
        bf16x8 af = *(const bf16x8*)(mid + (long)arow * 512 + k0);
        const unsigned short* Wb = WTbf + (long)(256 + hi * 256) * 256;
#pragma unroll
        for (int ni = 0; ni < 4; ni++) {
            int cn = wid * 64 + ni * 16 + l15;
            bf16x8 bfr = *(const bf16x8*)(Wb + (long)cn * 256 + innerk);
            acc[ni] = __builtin_amdgcn_mfma_f32_16x16x32_bf16(af, bfr, acc[ni], 0, 0, 0);
        }
    }

    float cv[4], gv[4], bv[4], tvx[4][4];
#pragma unroll
    for (int ni = 0; ni < 4; ni++) {
        int c = wid * 64 + ni * 16 + l15;
        cv[ni] = carr[c];
        gv[ni] = gamma[c];
        bv[ni] = beta[c];
    }
#pragma unroll
    for (int r = 0; r < 4; r++) {
        int row = l4 * 4 + r;
        int bb = row & 7;
        int nid = op_ids[bb * 16383];
#pragma unroll
        for (int ni = 0; ni < 4; ni++)
            tvx[r][ni] = T0[(long)nid * 256 + wid * 64 + ni * 16 + l15];
    }

#pragma unroll
    for (int r = 0; r < 4; r++) {
        int row = l4 * 4 + r;
        float s = 0.f, s2 = 0.f;
#pragma unroll
        for (int ni = 0; ni < 4; ni++) {
            float hh = fmaxf(acc[ni][r] + tvx[r][ni] + cv[ni], 0.f);
            acc[ni][r] = hh;
            s += hh;
            s2 += hh * hh;
        }
#pragma unroll
        for (int m = 1; m < 16; m <<= 1) {
            s += __shfl_xor(s, m);
            s2 += __shfl_xor(s2, m);
        }
        if (l15 == 0) {
            s_part[wid][row][0] = s;
            s_part[wid][row][1] = s2;
        }
    }
    __syncthreads();

#pragma unroll
    for (int r = 0; r < 4; r++) {
        int row = l4 * 4 + r;
        if (row < 8) {
            float s = s_part[0][row][0] + s_part[1][row][0] + s_part[2][row][0] + s_part[3][row][0];
            float s2 = s_part[0][row][1] + s_part[1][row][1] + s_part[2][row][1] + s_part[3][row][1];
            float mu = s * (1.f / 256.f);
            float rs = rsqrtf(s2 * (1.f / 256.f) - mu * mu + 1e-5f);
#pragma unroll
            for (int ni = 0; ni < 4; ni++) {
                int c = wid * 64 + ni * 16 + l15;
                out[row * 256 + c] = (acc[ni][r] - mu) * rs * gv[ni] + bv[ni];
            }
        }
    }
}

extern "C" void kernel_launch(void* const* d_in, const int* in_sizes, int n_in,
                              void* d_out, int out_size, void* d_ws, size_t ws_size,
                              hipStream_t stream) {
    const int* leaf_ids = (const int*)d_in[0];
    const int* op_ids = (const int*)d_in[1];
    const float* tok = (const float*)d_in[2];
    const float* dep = (const float*)d_in[3];
    const float* idx = (const float*)d_in[4];
    const float* W = (const float*)d_in[5];
    const float* bvec = (const float*)d_in[6];
    const float* gamma = (const float*)d_in[7];
    const float* beta = (const float*)d_in[8];
    float* out = (float*)d_out;

    char* ws = (char*)d_ws;
    float* T = (float*)(ws);                                             // 3 MB (T0|T1|T2)
    unsigned short* WTbf = (unsigned short*)(ws + 3u * 1024 * 1024);     // 384 KB
    unsigned short* tokbf = (unsigned short*)(ws + 3u * 1024 * 1024 + 512 * 1024);  // 512 KB
    float* carr = (float*)(ws + 4u * 1024 * 1024 + 64 * 1024);           // 14 KB
    unsigned short* mid = (unsigned short*)(ws + 6u * 1024 * 1024);      // 8 KB
    unsigned short* ebufA = (unsigned short*)(ws + 8u * 1024 * 1024);    // 16 MB
    unsigned short* ebufB = (unsigned short*)(ws + 40u * 1024 * 1024);   // 8 MB

    k_prep<<<318, 256, 0, stream>>>(tok, W, dep, idx, bvec, tokbf, WTbf, carr);
    k_ttmm<<<dim3(32, 3), 256, 0, stream>>>(tokbf, WTbf, T);

    // levels 13+12 -> ebufA (4096 rows/batch)
    k_level12f<<<dim3(64, 8), 256, 0, stream>>>(leaf_ids, op_ids, T, carr, gamma, beta, WTbf,
                                                ebufA);
    // level 11 -> ebufB (2048 rows/batch)
    k_level<4><<<dim3(32, 8), 256, 0, stream>>>(ebufA, ebufB, op_ids, T, carr + 11 * 256, gamma,
                                                beta, WTbf, 2048);
    // level 10 -> ebufA (1024 rows/batch)
    k_level<2><<<dim3(32, 8), 256, 0, stream>>>(ebufB, ebufA, op_ids, T, carr + 10 * 256, gamma,
                                                beta, WTbf, 1024);
    // level 9 -> ebufB (512 rows/batch)
    k_level<2><<<dim3(16, 8), 256, 0, stream>>>(ebufA, ebufB, op_ids, T, carr + 9 * 256, gamma,
                                                beta, WTbf, 512);
    // level 8 -> ebufA (256 rows/batch)
    k_level<2><<<dim3(8, 8), 256, 0, stream>>>(ebufB, ebufA, op_ids, T, carr + 8 * 256, gamma,
                                               beta, WTbf, 256);
    // levels 7..1 (16 blocks: batch x subtree-half) -> mid
    k_tail<<<16, 512, 0, stream>>>(ebufA, op_ids, T, carr, gamma, beta, WTbf, mid);
    // level 0
    k_root<<<1, 256, 0, stream>>>(mid, op_ids, T, carr, gamma, beta, WTbf, out);
}

// Round 9
// 300.903 us; speedup vs baseline: 1.1931x; 1.1343x over previous
//
#include <hip/hip_runtime.h>

typedef float f32x4 __attribute__((ext_vector_type(4)));
typedef short bf16x8 __attribute__((ext_vector_type(8)));

__device__ inline unsigned short f2bf(float f) {
    unsigned int u = __builtin_bit_cast(unsigned int, f);
    unsigned int r = (u + 0x7FFFu + ((u >> 16) & 1u)) >> 16;
    return (unsigned short)r;
}

// ---------------- Combined prep: tok->bf16 | W transpose->bf16 | carr vectors
__global__ __launch_bounds__(256) void k_prep(const float* __restrict__ tok,
                                              const float* __restrict__ W,
                                              const float* __restrict__ dep,
                                              const float* __restrict__ idx,
                                              const float* __restrict__ bvec,
                                              unsigned short* __restrict__ tokbf,
                                              unsigned short* __restrict__ WTbf,
                                              float* __restrict__ carr) {
    __shared__ float s_tile[64][65];
    int bx = blockIdx.x;
    if (bx < 256) {
        int i = bx * 256 + threadIdx.x;
        const float4 v = *(const float4*)(tok + (long)i * 4);
        ushort4 o;
        o.x = f2bf(v.x); o.y = f2bf(v.y); o.z = f2bf(v.z); o.w = f2bf(v.w);
        *(ushort4*)(tokbf + (long)i * 4) = o;
    } else if (bx < 304) {
        int bb = bx - 256;
        int sec = bb >> 4;
        int tt = bb & 15;
        int k0 = (tt >> 2) * 64, j0 = (tt & 3) * 64;
        int tx = threadIdx.x & 63, ty = threadIdx.x >> 6;
#pragma unroll
        for (int r = 0; r < 16; r++) {
            int kk = ty * 16 + r;
            s_tile[kk][tx] = W[(sec * 256 + k0 + kk) * 256 + j0 + tx];
        }
        __syncthreads();
#pragma unroll
        for (int r = 0; r < 16; r++) {
            int jj = ty * 16 + r;
            WTbf[(sec * 256 + j0 + jj) * 256 + k0 + tx] = f2bf(s_tile[tx][jj]);
        }
    } else {
        int d = bx - 304;
        int j = threadIdx.x;
        float acc = bvec[j];
#pragma unroll 4
        for (int k = 0; k < 256; k++) {
            float dv = dep[(d + 1) * 256 + k];
            acc += dv * (W[(768 + k) * 256 + j] + W[(1280 + k) * 256 + j]);
            acc += idx[k] * W[(1024 + k) * 256 + j];
            acc += idx[256 + k] * W[(1536 + k) * 256 + j];
        }
        if (d == 13) {
#pragma unroll 4
            for (int k = 0; k < 256; k++) {
                float dv = dep[14 * 256 + k];
                acc += dv * (W[(256 + k) * 256 + j] + W[(512 + k) * 256 + j]);
            }
        }
        carr[d * 256 + j] = acc;
    }
}

// ---------------- T tables via MFMA: T[sec][1024][256] = tokbf @ Wsec
__global__ __launch_bounds__(256) void k_ttmm(const unsigned short* __restrict__ tokbf,
                                              const unsigned short* __restrict__ WTbf,
                                              float* __restrict__ T) {
    int wid = threadIdx.x >> 6, lane = threadIdx.x & 63;
    int l15 = lane & 15, l4 = lane >> 4;
    int row0 = blockIdx.x * 32;
    int sec = blockIdx.y;

    f32x4 acc[2][4] = {};
    for (int kk = 0; kk < 8; kk++) {
        int k0 = kk * 32 + l4 * 8;
        bf16x8 af[2], bfr[4];
#pragma unroll
        for (int mi = 0; mi < 2; mi++)
            af[mi] = *(const bf16x8*)(tokbf + (long)(row0 + mi * 16 + l15) * 256 + k0);
#pragma unroll
        for (int ni = 0; ni < 4; ni++)
            bfr[ni] = *(const bf16x8*)(WTbf + (long)(sec * 256 + wid * 64 + ni * 16 + l15) * 256 + k0);
#pragma unroll
        for (int mi = 0; mi < 2; mi++)
#pragma unroll
            for (int ni = 0; ni < 4; ni++)
                acc[mi][ni] = __builtin_amdgcn_mfma_f32_16x16x32_bf16(af[mi], bfr[ni],
                                                                     acc[mi][ni], 0, 0, 0);
    }
#pragma unroll
    for (int mi = 0; mi < 2; mi++)
#pragma unroll
        for (int r = 0; r < 4; r++) {
            int row = row0 + mi * 16 + l4 * 4 + r;
#pragma unroll
            for (int ni = 0; ni < 4; ni++) {
                int c = wid * 64 + ni * 16 + l15;
                T[(long)sec * 262144 + (long)row * 256 + c] = acc[mi][ni][r];
            }
        }
}

// ---------------- Fused level 13+12
__global__ __launch_bounds__(256) void k_level12f(const int* __restrict__ leaf_ids,
                                                  const int* __restrict__ op_ids,
                                                  const float* __restrict__ T,
                                                  const float* __restrict__ carr,
                                                  const float* __restrict__ gamma,
                                                  const float* __restrict__ beta,
                                                  const unsigned short* __restrict__ WTbf,
                                                  unsigned short* __restrict__ ebuf_out) {
    __shared__ unsigned short sA[128 * 256];
    __shared__ int s_nid13[128];
    __shared__ int s_leaf[256];
    __shared__ int s_nid[64];
    __shared__ float s_part[4][64][2];
    int b = blockIdx.y;
    int row0 = blockIdx.x * 64;
    int t = threadIdx.x;
    int wid = t >> 6, lane = t & 63;
    int l15 = lane & 15, l4 = lane >> 4;
    const float* T0 = T;
    const float* T1 = T + 262144;
    const float* T2 = T + 524288;

    if (t < 128) s_nid13[t] = op_ids[b * 16383 + 8191 + 2 * row0 + t];
    s_leaf[t] = leaf_ids[b * 16384 + 4 * row0 + t];
    if (t < 64) s_nid[t] = op_ids[b * 16383 + 4095 + row0 + t];
    __syncthreads();

    {
        const float* c13 = carr + 13 * 256;
        float4 dd = *(const float4*)(c13 + 4 * lane);
        float4 g4 = *(const float4*)(gamma + 4 * lane);
        float4 b4 = *(const float4*)(beta + 4 * lane);
#pragma unroll 2
        for (int j = 0; j < 32; j++) {
            int node = wid * 32 + j;
            int nid = s_nid13[node];
            int ll = s_leaf[2 * node], lr = s_leaf[2 * node + 1];
            float4 a = *(const float4*)(T0 + (long)nid * 256 + 4 * lane);
            float4 bb = *(const float4*)(T1 + (long)ll * 256 + 4 * lane);
            float4 cc = *(const float4*)(T2 + (long)lr * 256 + 4 * lane);
            float v0 = fmaxf(a.x + bb.x + cc.x + dd.x, 0.f);
            float v1 = fmaxf(a.y + bb.y + cc.y + dd.y, 0.f);
            float v2 = fmaxf(a.z + bb.z + cc.z + dd.z, 0.f);
            float v3 = fmaxf(a.w + bb.w + cc.w + dd.w, 0.f);
            float s = v0 + v1 + v2 + v3;
            float s2 = v0 * v0 + v1 * v1 + v2 * v2 + v3 * v3;
#pragma unroll
            for (int m = 1; m < 64; m <<= 1) {
                s += __shfl_xor(s, m);
                s2 += __shfl_xor(s2, m);
            }
            float mu = s * (1.f / 256.f);
            float rs = rsqrtf(s2 * (1.f / 256.f) - mu * mu + 1e-5f);
            ushort4 o;
            o.x = f2bf((v0 - mu) * rs * g4.x + b4.x);
            o.y = f2bf((v1 - mu) * rs * g4.y + b4.y);
            o.z = f2bf((v2 - mu) * rs * g4.z + b4.z);
            o.w = f2bf((v3 - mu) * rs * g4.w + b4.w);
            *(ushort4*)((char*)sA + node * 512 + ((8 * lane) ^ (((node >> 1) & 7) << 4))) = o;
        }
    }
    __syncthreads();

    f32x4 acc[4][4] = {};
    for (int kk = 0; kk < 16; kk++) {
        int k0 = kk * 32 + l4 * 8;
        int hi = k0 >> 8;
        int binr = (k0 & 255) * 2;
        bf16x8 af[4], bfr[4];
#pragma unroll
        for (int mi = 0; mi < 4; mi++) {
            int node = 2 * (mi * 16 + l15) + hi;
            af[mi] = *(const bf16x8*)((const char*)sA + node * 512 + (binr ^ (((node >> 1) & 7) << 4)));
        }
        const unsigned short* Wb = WTbf + (long)(256 + hi * 256) * 256;
        int innerk = k0 & 255;
#pragma unroll
        for (int ni = 0; ni < 4; ni++) {
            int cn = wid * 64 + ni * 16 + l15;
            bfr[ni] = *(const bf16x8*)(Wb + (long)cn * 256 + innerk);
        }
#pragma unroll
        for (int mi = 0; mi < 4; mi++)
#pragma unroll
            for (int ni = 0; ni < 4; ni++)
                acc[mi][ni] = __builtin_amdgcn_mfma_f32_16x16x32_bf16(af[mi], bfr[ni],
                                                                     acc[mi][ni], 0, 0, 0);
    }

    const float* carr_d = carr + 12 * 256;
    float cv[4], gv[4], bv[4];
#pragma unroll
    for (int ni = 0; ni < 4; ni++) {
        int c = wid * 64 + ni * 16 + l15;
        cv[ni] = carr_d[c];
        gv[ni] = gamma[c];
        bv[ni] = beta[c];
    }

#pragma unroll
    for (int mi = 0; mi < 4; mi++) {
#pragma unroll
        for (int r = 0; r < 4; r++) {
            int row = mi * 16 + l4 * 4 + r;
            int nid = s_nid[row];
            float s = 0.f, s2 = 0.f;
#pragma unroll
            for (int ni = 0; ni < 4; ni++) {
                int c = wid * 64 + ni * 16 + l15;
                float h = acc[mi][ni][r] + T0[(long)nid * 256 + c] + cv[ni];
                h = fmaxf(h, 0.f);
                acc[mi][ni][r] = h;
                s += h;
                s2 += h * h;
            }
#pragma unroll
            for (int m = 1; m < 16; m <<= 1) {
                s += __shfl_xor(s, m);
                s2 += __shfl_xor(s2, m);
            }
            if (l15 == 0) {
                s_part[wid][row][0] = s;
                s_part[wid][row][1] = s2;
            }
        }
    }
    __syncthreads();

#pragma unroll
    for (int mi = 0; mi < 4; mi++) {
#pragma unroll
        for (int r = 0; r < 4; r++) {
            int row = mi * 16 + l4 * 4 + r;
            float s = s_part[0][row][0] + s_part[1][row][0] + s_part[2][row][0] + s_part[3][row][0];
            float s2 = s_part[0][row][1] + s_part[1][row][1] + s_part[2][row][1] + s_part[3][row][1];
            float mu = s * (1.f / 256.f);
            float rs = rsqrtf(s2 * (1.f / 256.f) - mu * mu + 1e-5f);
            unsigned short* o = ebuf_out + ((long)b * 4096 + row0 + row) * 256;
#pragma unroll
            for (int ni = 0; ni < 4; ni++) {
                int c = wid * 64 + ni * 16 + l15;
                o[c] = f2bf((acc[mi][ni][r] - mu) * rs * gv[ni] + bv[ni]);
            }
        }
    }
}

// ---------------- Levels 11..8: MFMA GEMM + gather + relu + LN (MT*16 rows per block)
template <int MT>
__global__ __launch_bounds__(256) void k_level(const unsigned short* __restrict__ ebuf_prev,
                                               unsigned short* __restrict__ ebuf_out,
                                               const int* __restrict__ op_ids,
                                               const float* __restrict__ T0,
                                               const float* __restrict__ carr_d,
                                               const float* __restrict__ gamma,
                                               const float* __restrict__ beta,
                                               const unsigned short* __restrict__ WTbf,
                                               int n) {
    int wid = threadIdx.x >> 6, lane = threadIdx.x & 63;
    int b = blockIdx.y;
    int row0 = blockIdx.x * (MT * 16);
    int l15 = lane & 15, l4 = lane >> 4;

    __shared__ int s_nid[MT * 16];
    __shared__ float s_part[4][MT * 16][2];

    if (threadIdx.x < MT * 16)
        s_nid[threadIdx.x] = op_ids[b * 16383 + (n - 1) + row0 + threadIdx.x];
    __syncthreads();

    const unsigned short* X = ebuf_prev + (long)b * (2 * (long)n) * 256;

    f32x4 acc[MT][4] = {};

    for (int kk = 0; kk < 16; kk++) {
        int k0 = kk * 32 + l4 * 8;
        int hi = k0 >> 8;
        int innerk = k0 & 255;
        bf16x8 af[MT], bfr[4];
#pragma unroll
        for (int mi = 0; mi < MT; mi++) {
            int r = row0 + mi * 16 + l15;
            af[mi] = *(const bf16x8*)(X + (long)r * 512 + k0);
        }
        const unsigned short* Wb = WTbf + (long)(256 + hi * 256) * 256;
#pragma unroll
        for (int ni = 0; ni < 4; ni++) {
            int cn = wid * 64 + ni * 16 + l15;
            bfr[ni] = *(const bf16x8*)(Wb + (long)cn * 256 + innerk);
        }
#pragma unroll
        for (int mi = 0; mi < MT; mi++)
#pragma unroll
            for (int ni = 0; ni < 4; ni++)
                acc[mi][ni] = __builtin_amdgcn_mfma_f32_16x16x32_bf16(af[mi], bfr[ni],
                                                                     acc[mi][ni], 0, 0, 0);
    }

    float cv[4], gv[4], bv[4];
#pragma unroll
    for (int ni = 0; ni < 4; ni++) {
        int c = wid * 64 + ni * 16 + l15;
        cv[ni] = carr_d[c];
        gv[ni] = gamma[c];
        bv[ni] = beta[c];
    }

#pragma unroll
    for (int mi = 0; mi < MT; mi++) {
#pragma unroll
        for (int r = 0; r < 4; r++) {
            int row = mi * 16 + l4 * 4 + r;
            int nid = s_nid[row];
            float s = 0.f, s2 = 0.f;
#pragma unroll
            for (int ni = 0; ni < 4; ni++) {
                int c = wid * 64 + ni * 16 + l15;
                float h = acc[mi][ni][r] + T0[(long)nid * 256 + c] + cv[ni];
                h = fmaxf(h, 0.f);
                acc[mi][ni][r] = h;
                s += h;
                s2 += h * h;
            }
#pragma unroll
            for (int m = 1; m < 16; m <<= 1) {
                s += __shfl_xor(s, m);
                s2 += __shfl_xor(s2, m);
            }
            if (l15 == 0) {
                s_part[wid][row][0] = s;
                s_part[wid][row][1] = s2;
            }
        }
    }
    __syncthreads();

#pragma unroll
    for (int mi = 0; mi < MT; mi++) {
#pragma unroll
        for (int r = 0; r < 4; r++) {
            int row = mi * 16 + l4 * 4 + r;
            float s = s_part[0][row][0] + s_part[1][row][0] + s_part[2][row][0] + s_part[3][row][0];
            float s2 = s_part[0][row][1] + s_part[1][row][1] + s_part[2][row][1] + s_part[3][row][1];
            float mu = s * (1.f / 256.f);
            float rs = rsqrtf(s2 * (1.f / 256.f) - mu * mu + 1e-5f);
            unsigned short* o = ebuf_out + ((long)b * n + row0 + row) * 256;
#pragma unroll
            for (int ni = 0; ni < 4; ni++) {
                int c = wid * 64 + ni * 16 + l15;
                o[c] = f2bf((acc[mi][ni][r] - mu) * rs * gv[ni] + bv[ni]);
            }
        }
    }
}

// ---------------- Subtree tail: levels 7..1. 16 blocks (block = (batch, half)), 512 threads,
// 8 waves x 32 cols. B (WTbf) loaded ONCE into registers (breg, 128 VGPR) — removes the
// per-level HBM-latency-bound B reload that capped R8 at 27 GB/s. amdgpu_waves_per_eu(2,2)
// lifts the allocator's 128-VGPR heuristic cap (8-wave block = exactly 2 waves/SIMD -> HW
// supports 256 VGPR/wave).
__global__ __attribute__((amdgpu_waves_per_eu(2, 2))) __launch_bounds__(512)
void k_tail(const unsigned short* __restrict__ prev,
            const int* __restrict__ op_ids,
            const float* __restrict__ T0,
            const float* __restrict__ carr,
            const float* __restrict__ gamma,
            const float* __restrict__ beta,
            const unsigned short* __restrict__ WTbf,
            unsigned short* __restrict__ mid) {
    __shared__ unsigned short sA[64 * 256];
    __shared__ unsigned short sB[64 * 256];
    __shared__ int s_nid_all[255];
    __shared__ float s_part[8][64][2];
    int b = blockIdx.x >> 1;
    int h = blockIdx.x & 1;
    int t = threadIdx.x;
    int wid = t >> 6, lane = t & 63;
    int l15 = lane & 15, l4 = lane >> 4;

    // B fragments for this wave's 32 cols, ALL 16 ksteps, held in registers across levels
    bf16x8 breg[16][2];
#pragma unroll
    for (int kk = 0; kk < 16; kk++) {
        int k0 = kk * 32 + l4 * 8;
        int hi = k0 >> 8;
        int innerk = k0 & 255;
        const unsigned short* Wb = WTbf + (long)(256 + hi * 256) * 256;
#pragma unroll
        for (int ni = 0; ni < 2; ni++) {
            int cn = wid * 32 + ni * 16 + l15;
            breg[kk][ni] = *(const bf16x8*)(Wb + (long)cn * 256 + innerk);
        }
    }

    if (t < 255) s_nid_all[t] = op_ids[b * 16383 + t];
    float gv[2], bv[2];
#pragma unroll
    for (int ni = 0; ni < 2; ni++) {
        int c = wid * 32 + ni * 16 + l15;
        gv[ni] = gamma[c];
        bv[ni] = beta[c];
    }
    __syncthreads();

    unsigned short* cur = sA;
    unsigned short* nxt = sB;

    // ---- Level 7: 64 local rows (global level-7 nodes h*64 + [0,64)) from global X -> sA
    {
        const unsigned short* X = prev + ((long)b * 256 + h * 128) * 256;
        const float* carr7 = carr + 7 * 256;
        float cv7[2];
#pragma unroll
        for (int ni = 0; ni < 2; ni++) cv7[ni] = carr7[wid * 32 + ni * 16 + l15];

        float tv[4][4][2];
#pragma unroll
        for (int mi = 0; mi < 4; mi++)
#pragma unroll
            for (int r = 0; r < 4; r++) {
                int row = mi * 16 + l4 * 4 + r;
                int nid = s_nid_all[127 + h * 64 + row];
#pragma unroll
                for (int ni = 0; ni < 2; ni++)
                    tv[mi][r][ni] = T0[(long)nid * 256 + wid * 32 + ni * 16 + l15];
            }

        f32x4 acc[4][2] = {};
#pragma unroll
        for (int kk = 0; kk < 16; kk++) {
            int k0 = kk * 32 + l4 * 8;
            bf16x8 af[4];
#pragma unroll
            for (int mi = 0; mi < 4; mi++)
                af[mi] = *(const bf16x8*)(X + (long)(mi * 16 + l15) * 512 + k0);
#pragma unroll
            for (int mi = 0; mi < 4; mi++)
#pragma unroll
                for (int ni = 0; ni < 2; ni++)
                    acc[mi][ni] = __builtin_amdgcn_mfma_f32_16x16x32_bf16(af[mi], breg[kk][ni],
                                                                         acc[mi][ni], 0, 0, 0);
        }

#pragma unroll
        for (int mi = 0; mi < 4; mi++)
#pragma unroll
            for (int r = 0; r < 4; r++) {
                float s = 0.f, s2 = 0.f;
#pragma unroll
                for (int ni = 0; ni < 2; ni++) {
                    float hh = fmaxf(acc[mi][ni][r] + tv[mi][r][ni] + cv7[ni], 0.f);
                    acc[mi][ni][r] = hh;
                    s += hh;
                    s2 += hh * hh;
                }
#pragma unroll
                for (int m = 1; m < 16; m <<= 1) {
                    s += __shfl_xor(s, m);
                    s2 += __shfl_xor(s2, m);
                }
                if (l15 == 0) {
                    int row = mi * 16 + l4 * 4 + r;
                    s_part[wid][row][0] = s;
                    s_part[wid][row][1] = s2;
                }
            }
        __syncthreads();

#pragma unroll
        for (int mi = 0; mi < 4; mi++)
#pragma unroll
            for (int r = 0; r < 4; r++) {
                int row = mi * 16 + l4 * 4 + r;
                float s = 0.f, s2 = 0.f;
#pragma unroll
                for (int w = 0; w < 8; w++) {
                    s += s_part[w][row][0];
                    s2 += s_part[w][row][1];
                }
                float mu = s * (1.f / 256.f);
                float rs = rsqrtf(s2 * (1.f / 256.f) - mu * mu + 1e-5f);
#pragma unroll
                for (int ni = 0; ni < 2; ni++) {
                    int c = wid * 32 + ni * 16 + l15;
                    unsigned short val = f2bf((acc[mi][ni][r] - mu) * rs * gv[ni] + bv[ni]);
                    *(unsigned short*)((char*)sA + row * 512 +
                                       ((c * 2) ^ (((row >> 1) & 7) << 4))) = val;
                }
            }
        __syncthreads();
    }

    // ---- Levels 6..1: m = 2^(ld-1) local rows; LDS ping-pong; ld==1 writes mid
    for (int ld = 6; ld >= 1; ld--) {
        int ng = 1 << ld;   // global nodes at this level
        int m = ng >> 1;    // local rows (this subtree half)
        int mtiles = (m + 15) >> 4;

        float tv[2][4][2];
#pragma unroll
        for (int mi = 0; mi < 2; mi++)
            if (mi < mtiles)
#pragma unroll
                for (int r = 0; r < 4; r++) {
                    int row = mi * 16 + l4 * 4 + r;
                    int rc = row < m ? row : m - 1;
                    int nid = s_nid_all[(ng - 1) + h * m + rc];
#pragma unroll
                    for (int ni = 0; ni < 2; ni++)
                        tv[mi][r][ni] = T0[(long)nid * 256 + wid * 32 + ni * 16 + l15];
                }

        f32x4 acc[2][2] = {};
#pragma unroll
        for (int kk = 0; kk < 16; kk++) {
            int k0 = kk * 32 + l4 * 8;
            int hi = k0 >> 8;
            int innerk = k0 & 255;
            int binr = innerk * 2;
            bf16x8 af[2];
#pragma unroll
            for (int mi = 0; mi < 2; mi++)
                if (mi < mtiles) {
                    int node = 2 * (mi * 16 + l15) + hi;
                    af[mi] = *(const bf16x8*)((const char*)cur + node * 512 +
                                              (binr ^ (((node >> 1) & 7) << 4)));
                }
#pragma unroll
            for (int mi = 0; mi < 2; mi++)
                if (mi < mtiles)
#pragma unroll
                    for (int ni = 0; ni < 2; ni++)
                        acc[mi][ni] = __builtin_amdgcn_mfma_f32_16x16x32_bf16(af[mi], breg[kk][ni],
                                                                             acc[mi][ni], 0, 0, 0);
        }

        const float* carr_d = carr + ld * 256;
        float cv[2];
#pragma unroll
        for (int ni = 0; ni < 2; ni++) cv[ni] = carr_d[wid * 32 + ni * 16 + l15];

#pragma unroll
        for (int mi = 0; mi < 2; mi++)
            if (mi < mtiles)
#pragma unroll
                for (int r = 0; r < 4; r++) {
                    float s = 0.f, s2 = 0.f;
#pragma unroll
                    for (int ni = 0; ni < 2; ni++) {
                        float hh = fmaxf(acc[mi][ni][r] + tv[mi][r][ni] + cv[ni], 0.f);
                        acc[mi][ni][r] = hh;
                        s += hh;
                        s2 += hh * hh;
                    }
#pragma unroll
                    for (int m2 = 1; m2 < 16; m2 <<= 1) {
                        s += __shfl_xor(s, m2);
                        s2 += __shfl_xor(s2, m2);
                    }
                    if (l15 == 0) {
                        int row = mi * 16 + l4 * 4 + r;
                        s_part[wid][row][0] = s;
                        s_part[wid][row][1] = s2;
                    }
                }
        __syncthreads();

#pragma unroll
        for (int mi = 0; mi < 2; mi++)
            if (mi < mtiles)
#pragma unroll
                for (int r = 0; r < 4; r++) {
                    int row = mi * 16 + l4 * 4 + r;
                    if (row < m) {
                        float s = 0.f, s2 = 0.f;
#pragma unroll
                        for (int w = 0; w < 8; w++) {
                            s += s_part[w][row][0];
                            s2 += s_part[w][row][1];
                        }
                        float mu = s * (1.f / 256.f);
                        float rs = rsqrtf(s2 * (1.f / 256.f) - mu * mu + 1e-5f);
#pragma unroll
                        for (int ni = 0; ni < 2; ni++) {
                            int c = wid * 32 + ni * 16 + l15;
                            float val = (acc[mi][ni][r] - mu) * rs * gv[ni] + bv[ni];
                            if (ld == 1) {
                                mid[(long)(b * 2 + h) * 256 + c] = f2bf(val);
                            } else {
                                *(unsigned short*)((char*)nxt + row * 512 +
                                                   ((c * 2) ^ (((row >> 1) & 7) << 4))) = f2bf(val);
                            }
                        }
                    }
                }
        __syncthreads();
        unsigned short* tmp = cur;
        cur = nxt;
        nxt = tmp;
    }
}

// ---------------- Root (level 0): one block, 4 waves. GEMM 8 rows (batches) x K=512 x N=256.
__global__ __launch_bounds__(256) void k_root(const unsigned short* __restrict__ mid,
                                              const int* __restrict__ op_ids,
                                              const float* __restrict__ T0,
                                              const float* __restrict__ carr,
                                              const float* __restrict__ gamma,
                                              const float* __restrict__ beta,
                                              const unsigned short* __restrict__ WTbf,
                                              float* __restrict__ out) {
    __shared__ float s_part[4][16][2];
    int t = threadIdx.x;
    int wid = t >> 6, lane = t & 63;
    int l15 = lane & 15, l4 = lane >> 4;

    f32x4 acc[4] = {};
    for (int kk = 0; kk < 16; kk++) {
        int k0 = kk * 32 + l4 * 8;
        int hi = k0 >> 8;
        int innerk = k0 & 255;
        int arow = l15 & 7;  // rows 8..15 mirror 0..7; their outputs are discarded
        bf16x8 af = *(const bf16x8*)(mid + (long)arow * 512 + k0);
        const unsigned short* Wb = WTbf + (long)(256 + hi * 256) * 256;
#pragma unroll
        for (int ni = 0; ni < 4; ni++) {
            int cn = wid * 64 + ni * 16 + l15;
            bf16x8 bfr = *(const bf16x8*)(Wb + (long)cn * 256 + innerk);
            acc[ni] = __builtin_amdgcn_mfma_f32_16x16x32_bf16(af, bfr, acc[ni], 0, 0, 0);
        }
    }

    float cv[4], gv[4], bv[4], tvx[4][4];
#pragma unroll
    for (int ni = 0; ni < 4; ni++) {
        int c = wid * 64 + ni * 16 + l15;
        cv[ni] = carr[c];
        gv[ni] = gamma[c];
        bv[ni] = beta[c];
    }
#pragma unroll
    for (int r = 0; r < 4; r++) {
        int row = l4 * 4 + r;
        int bb = row & 7;
        int nid = op_ids[bb * 16383];
#pragma unroll
        for (int ni = 0; ni < 4; ni++)
            tvx[r][ni] = T0[(long)nid * 256 + wid * 64 + ni * 16 + l15];
    }

#pragma unroll
    for (int r = 0; r < 4; r++) {
        int row = l4 * 4 + r;
        float s = 0.f, s2 = 0.f;
#pragma unroll
        for (int ni = 0; ni < 4; ni++) {
            float hh = fmaxf(acc[ni][r] + tvx[r][ni] + cv[ni], 0.f);
            acc[ni][r] = hh;
            s += hh;
            s2 += hh * hh;
        }
#pragma unroll
        for (int m = 1; m < 16; m <<= 1) {
            s += __shfl_xor(s, m);
            s2 += __shfl_xor(s2, m);
        }
        if (l15 == 0) {
            s_part[wid][row][0] = s;
            s_part[wid][row][1] = s2;
        }
    }
    __syncthreads();

#pragma unroll
    for (int r = 0; r < 4; r++) {
        int row = l4 * 4 + r;
        if (row < 8) {
            float s = s_part[0][row][0] + s_part[1][row][0] + s_part[2][row][0] + s_part[3][row][0];
            float s2 = s_part[0][row][1] + s_part[1][row][1] + s_part[2][row][1] + s_part[3][row][1];
            float mu = s * (1.f / 256.f);
            float rs = rsqrtf(s2 * (1.f / 256.f) - mu * mu + 1e-5f);
#pragma unroll
            for (int ni = 0; ni < 4; ni++) {
                int c = wid * 64 + ni * 16 + l15;
                out[row * 256 + c] = (acc[ni][r] - mu) * rs * gv[ni] + bv[ni];
            }
        }
    }
}

extern "C" void kernel_launch(void* const* d_in, const int* in_sizes, int n_in,
                              void* d_out, int out_size, void* d_ws, size_t ws_size,
                              hipStream_t stream) {
    const int* leaf_ids = (const int*)d_in[0];
    const int* op_ids = (const int*)d_in[1];
    const float* tok = (const float*)d_in[2];
    const float* dep = (const float*)d_in[3];
    const float* idx = (const float*)d_in[4];
    const float* W = (const float*)d_in[5];
    const float* bvec = (const float*)d_in[6];
    const float* gamma = (const float*)d_in[7];
    const float* beta = (const float*)d_in[8];
    float* out = (float*)d_out;

    char* ws = (char*)d_ws;
    float* T = (float*)(ws);                                             // 3 MB (T0|T1|T2)
    unsigned short* WTbf = (unsigned short*)(ws + 3u * 1024 * 1024);     // 384 KB
    unsigned short* tokbf = (unsigned short*)(ws + 3u * 1024 * 1024 + 512 * 1024);  // 512 KB
    float* carr = (float*)(ws + 4u * 1024 * 1024 + 64 * 1024);           // 14 KB
    unsigned short* mid = (unsigned short*)(ws + 6u * 1024 * 1024);      // 8 KB
    unsigned short* ebufA = (unsigned short*)(ws + 8u * 1024 * 1024);    // 16 MB
    unsigned short* ebufB = (unsigned short*)(ws + 40u * 1024 * 1024);   // 8 MB

    k_prep<<<318, 256, 0, stream>>>(tok, W, dep, idx, bvec, tokbf, WTbf, carr);
    k_ttmm<<<dim3(32, 3), 256, 0, stream>>>(tokbf, WTbf, T);

    // levels 13+12 -> ebufA (4096 rows/batch)
    k_level12f<<<dim3(64, 8), 256, 0, stream>>>(leaf_ids, op_ids, T, carr, gamma, beta, WTbf,
                                                ebufA);
    // level 11 -> ebufB (2048 rows/batch)
    k_level<4><<<dim3(32, 8), 256, 0, stream>>>(ebufA, ebufB, op_ids, T, carr + 11 * 256, gamma,
                                                beta, WTbf, 2048);
    // level 10 -> ebufA (1024 rows/batch)
    k_level<2><<<dim3(32, 8), 256, 0, stream>>>(ebufB, ebufA, op_ids, T, carr + 10 * 256, gamma,
                                                beta, WTbf, 1024);
    // level 9 -> ebufB (512 rows/batch)
    k_level<2><<<dim3(16, 8), 256, 0, stream>>>(ebufA, ebufB, op_ids, T, carr + 9 * 256, gamma,
                                                beta, WTbf, 512);
    // level 8 -> ebufA (256 rows/batch)
    k_level<2><<<dim3(8, 8), 256, 0, stream>>>(ebufB, ebufA, op_ids, T, carr + 8 * 256, gamma,
                                               beta, WTbf, 256);
    // levels 7..1 (16 blocks: batch x subtree-half) -> mid
    k_tail<<<16, 512, 0, stream>>>(ebufA, op_ids, T, carr, gamma, beta, WTbf, mid);
    // level 0
    k_root<<<1, 256, 0, stream>>>(mid, op_ids, T, carr, gamma, beta, WTbf, out);
}

// Round 10
// 285.571 us; speedup vs baseline: 1.2571x; 1.0537x over previous
//
#include <hip/hip_runtime.h>

typedef float f32x4 __attribute__((ext_vector_type(4)));
typedef short bf16x8 __attribute__((ext_vector_type(8)));

__device__ inline unsigned short f2bf(float f) {
    unsigned int u = __builtin_bit_cast(unsigned int, f);
    unsigned int r = (u + 0x7FFFu + ((u >> 16) & 1u)) >> 16;
    return (unsigned short)r;
}

// ---------------- Combined prep: tok->bf16 | W transpose->bf16 | carr vectors
__global__ __launch_bounds__(256) void k_prep(const float* __restrict__ tok,
                                              const float* __restrict__ W,
                                              const float* __restrict__ dep,
                                              const float* __restrict__ idx,
                                              const float* __restrict__ bvec,
                                              unsigned short* __restrict__ tokbf,
                                              unsigned short* __restrict__ WTbf,
                                              float* __restrict__ carr) {
    __shared__ float s_tile[64][65];
    int bx = blockIdx.x;
    if (bx < 256) {
        int i = bx * 256 + threadIdx.x;
        const float4 v = *(const float4*)(tok + (long)i * 4);
        ushort4 o;
        o.x = f2bf(v.x); o.y = f2bf(v.y); o.z = f2bf(v.z); o.w = f2bf(v.w);
        *(ushort4*)(tokbf + (long)i * 4) = o;
    } else if (bx < 304) {
        int bb = bx - 256;
        int sec = bb >> 4;
        int tt = bb & 15;
        int k0 = (tt >> 2) * 64, j0 = (tt & 3) * 64;
        int tx = threadIdx.x & 63, ty = threadIdx.x >> 6;
#pragma unroll
        for (int r = 0; r < 16; r++) {
            int kk = ty * 16 + r;
            s_tile[kk][tx] = W[(sec * 256 + k0 + kk) * 256 + j0 + tx];
        }
        __syncthreads();
#pragma unroll
        for (int r = 0; r < 16; r++) {
            int jj = ty * 16 + r;
            WTbf[(sec * 256 + j0 + jj) * 256 + k0 + tx] = f2bf(s_tile[tx][jj]);
        }
    } else {
        int d = bx - 304;
        int j = threadIdx.x;
        float acc = bvec[j];
#pragma unroll 4
        for (int k = 0; k < 256; k++) {
            float dv = dep[(d + 1) * 256 + k];
            acc += dv * (W[(768 + k) * 256 + j] + W[(1280 + k) * 256 + j]);
            acc += idx[k] * W[(1024 + k) * 256 + j];
            acc += idx[256 + k] * W[(1536 + k) * 256 + j];
        }
        if (d == 13) {
#pragma unroll 4
            for (int k = 0; k < 256; k++) {
                float dv = dep[14 * 256 + k];
                acc += dv * (W[(256 + k) * 256 + j] + W[(512 + k) * 256 + j]);
            }
        }
        carr[d * 256 + j] = acc;
    }
}

// ---------------- T tables via MFMA: T[sec][1024][256] = tokbf @ Wsec
__global__ __launch_bounds__(256) void k_ttmm(const unsigned short* __restrict__ tokbf,
                                              const unsigned short* __restrict__ WTbf,
                                              float* __restrict__ T) {
    int wid = threadIdx.x >> 6, lane = threadIdx.x & 63;
    int l15 = lane & 15, l4 = lane >> 4;
    int row0 = blockIdx.x * 32;
    int sec = blockIdx.y;

    f32x4 acc[2][4] = {};
    for (int kk = 0; kk < 8; kk++) {
        int k0 = kk * 32 + l4 * 8;
        bf16x8 af[2], bfr[4];
#pragma unroll
        for (int mi = 0; mi < 2; mi++)
            af[mi] = *(const bf16x8*)(tokbf + (long)(row0 + mi * 16 + l15) * 256 + k0);
#pragma unroll
        for (int ni = 0; ni < 4; ni++)
            bfr[ni] = *(const bf16x8*)(WTbf + (long)(sec * 256 + wid * 64 + ni * 16 + l15) * 256 + k0);
#pragma unroll
        for (int mi = 0; mi < 2; mi++)
#pragma unroll
            for (int ni = 0; ni < 4; ni++)
                acc[mi][ni] = __builtin_amdgcn_mfma_f32_16x16x32_bf16(af[mi], bfr[ni],
                                                                     acc[mi][ni], 0, 0, 0);
    }
#pragma unroll
    for (int mi = 0; mi < 2; mi++)
#pragma unroll
        for (int r = 0; r < 4; r++) {
            int row = row0 + mi * 16 + l4 * 4 + r;
#pragma unroll
            for (int ni = 0; ni < 4; ni++) {
                int c = wid * 64 + ni * 16 + l15;
                T[(long)sec * 262144 + (long)row * 256 + c] = acc[mi][ni][r];
            }
        }
}

// ---------------- Fused level 13+12: 32 rows / 64 nodes per block (sA 32KB -> 4 blocks/CU)
__global__ __launch_bounds__(256) void k_level12f(const int* __restrict__ leaf_ids,
                                                  const int* __restrict__ op_ids,
                                                  const float* __restrict__ T,
                                                  const float* __restrict__ carr,
                                                  const float* __restrict__ gamma,
                                                  const float* __restrict__ beta,
                                                  const unsigned short* __restrict__ WTbf,
                                                  unsigned short* __restrict__ ebuf_out) {
    __shared__ unsigned short sA[64 * 256];
    __shared__ int s_nid13[64];
    __shared__ int s_leaf[128];
    __shared__ int s_nid[32];
    __shared__ float s_part[4][32][2];
    int b = blockIdx.y;
    int row0 = blockIdx.x * 32;
    int t = threadIdx.x;
    int wid = t >> 6, lane = t & 63;
    int l15 = lane & 15, l4 = lane >> 4;
    const float* T0 = T;
    const float* T1 = T + 262144;
    const float* T2 = T + 524288;

    if (t < 64) s_nid13[t] = op_ids[b * 16383 + 8191 + 2 * row0 + t];
    if (t < 128) s_leaf[t] = leaf_ids[b * 16384 + 4 * row0 + t];
    if (t < 32) s_nid[t] = op_ids[b * 16383 + 4095 + row0 + t];
    __syncthreads();

    {
        const float* c13 = carr + 13 * 256;
        float4 dd = *(const float4*)(c13 + 4 * lane);
        float4 g4 = *(const float4*)(gamma + 4 * lane);
        float4 b4 = *(const float4*)(beta + 4 * lane);
#pragma unroll 2
        for (int j = 0; j < 16; j++) {
            int node = wid * 16 + j;
            int nid = s_nid13[node];
            int ll = s_leaf[2 * node], lr = s_leaf[2 * node + 1];
            float4 a = *(const float4*)(T0 + (long)nid * 256 + 4 * lane);
            float4 bb = *(const float4*)(T1 + (long)ll * 256 + 4 * lane);
            float4 cc = *(const float4*)(T2 + (long)lr * 256 + 4 * lane);
            float v0 = fmaxf(a.x + bb.x + cc.x + dd.x, 0.f);
            float v1 = fmaxf(a.y + bb.y + cc.y + dd.y, 0.f);
            float v2 = fmaxf(a.z + bb.z + cc.z + dd.z, 0.f);
            float v3 = fmaxf(a.w + bb.w + cc.w + dd.w, 0.f);
            float s = v0 + v1 + v2 + v3;
            float s2 = v0 * v0 + v1 * v1 + v2 * v2 + v3 * v3;
#pragma unroll
            for (int m = 1; m < 64; m <<= 1) {
                s += __shfl_xor(s, m);
                s2 += __shfl_xor(s2, m);
            }
            float mu = s * (1.f / 256.f);
            float rs = rsqrtf(s2 * (1.f / 256.f) - mu * mu + 1e-5f);
            ushort4 o;
            o.x = f2bf((v0 - mu) * rs * g4.x + b4.x);
            o.y = f2bf((v1 - mu) * rs * g4.y + b4.y);
            o.z = f2bf((v2 - mu) * rs * g4.z + b4.z);
            o.w = f2bf((v3 - mu) * rs * g4.w + b4.w);
            *(ushort4*)((char*)sA + node * 512 + ((8 * lane) ^ (((node >> 1) & 7) << 4))) = o;
        }
    }
    __syncthreads();

    f32x4 acc[2][4] = {};
    for (int kk = 0; kk < 16; kk++) {
        int k0 = kk * 32 + l4 * 8;
        int hi = k0 >> 8;
        int binr = (k0 & 255) * 2;
        bf16x8 af[2], bfr[4];
#pragma unroll
        for (int mi = 0; mi < 2; mi++) {
            int node = 2 * (mi * 16 + l15) + hi;
            af[mi] = *(const bf16x8*)((const char*)sA + node * 512 + (binr ^ (((node >> 1) & 7) << 4)));
        }
        const unsigned short* Wb = WTbf + (long)(256 + hi * 256) * 256;
        int innerk = k0 & 255;
#pragma unroll
        for (int ni = 0; ni < 4; ni++) {
            int cn = wid * 64 + ni * 16 + l15;
            bfr[ni] = *(const bf16x8*)(Wb + (long)cn * 256 + innerk);
        }
#pragma unroll
        for (int mi = 0; mi < 2; mi++)
#pragma unroll
            for (int ni = 0; ni < 4; ni++)
                acc[mi][ni] = __builtin_amdgcn_mfma_f32_16x16x32_bf16(af[mi], bfr[ni],
                                                                     acc[mi][ni], 0, 0, 0);
    }

    const float* carr_d = carr + 12 * 256;
    float cv[4], gv[4], bv[4];
#pragma unroll
    for (int ni = 0; ni < 4; ni++) {
        int c = wid * 64 + ni * 16 + l15;
        cv[ni] = carr_d[c];
        gv[ni] = gamma[c];
        bv[ni] = beta[c];
    }

#pragma unroll
    for (int mi = 0; mi < 2; mi++) {
#pragma unroll
        for (int r = 0; r < 4; r++) {
            int row = mi * 16 + l4 * 4 + r;
            int nid = s_nid[row];
            float s = 0.f, s2 = 0.f;
#pragma unroll
            for (int ni = 0; ni < 4; ni++) {
                int c = wid * 64 + ni * 16 + l15;
                float h = acc[mi][ni][r] + T0[(long)nid * 256 + c] + cv[ni];
                h = fmaxf(h, 0.f);
                acc[mi][ni][r] = h;
                s += h;
                s2 += h * h;
            }
#pragma unroll
            for (int m = 1; m < 16; m <<= 1) {
                s += __shfl_xor(s, m);
                s2 += __shfl_xor(s2, m);
            }
            if (l15 == 0) {
                s_part[wid][row][0] = s;
                s_part[wid][row][1] = s2;
            }
        }
    }
    __syncthreads();

#pragma unroll
    for (int mi = 0; mi < 2; mi++) {
#pragma unroll
        for (int r = 0; r < 4; r++) {
            int row = mi * 16 + l4 * 4 + r;
            float s = s_part[0][row][0] + s_part[1][row][0] + s_part[2][row][0] + s_part[3][row][0];
            float s2 = s_part[0][row][1] + s_part[1][row][1] + s_part[2][row][1] + s_part[3][row][1];
            float mu = s * (1.f / 256.f);
            float rs = rsqrtf(s2 * (1.f / 256.f) - mu * mu + 1e-5f);
            unsigned short* o = ebuf_out + ((long)b * 4096 + row0 + row) * 256;
#pragma unroll
            for (int ni = 0; ni < 4; ni++) {
                int c = wid * 64 + ni * 16 + l15;
                o[c] = f2bf((acc[mi][ni][r] - mu) * rs * gv[ni] + bv[ni]);
            }
        }
    }
}

// ---------------- Levels 11..8: MFMA GEMM + gather + relu + LN (MT*16 rows per block)
template <int MT>
__global__ __launch_bounds__(256) void k_level(const unsigned short* __restrict__ ebuf_prev,
                                               unsigned short* __restrict__ ebuf_out,
                                               const int* __restrict__ op_ids,
                                               const float* __restrict__ T0,
                                               const float* __restrict__ carr_d,
                                               const float* __restrict__ gamma,
                                               const float* __restrict__ beta,
                                               const unsigned short* __restrict__ WTbf,
                                               int n) {
    int wid = threadIdx.x >> 6, lane = threadIdx.x & 63;
    int b = blockIdx.y;
    int row0 = blockIdx.x * (MT * 16);
    int l15 = lane & 15, l4 = lane >> 4;

    __shared__ int s_nid[MT * 16];
    __shared__ float s_part[4][MT * 16][2];

    if (threadIdx.x < MT * 16)
        s_nid[threadIdx.x] = op_ids[b * 16383 + (n - 1) + row0 + threadIdx.x];
    __syncthreads();

    const unsigned short* X = ebuf_prev + (long)b * (2 * (long)n) * 256;

    f32x4 acc[MT][4] = {};

    for (int kk = 0; kk < 16; kk++) {
        int k0 = kk * 32 + l4 * 8;
        int hi = k0 >> 8;
        int innerk = k0 & 255;
        bf16x8 af[MT], bfr[4];
#pragma unroll
        for (int mi = 0; mi < MT; mi++) {
            int r = row0 + mi * 16 + l15;
            af[mi] = *(const bf16x8*)(X + (long)r * 512 + k0);
        }
        const unsigned short* Wb = WTbf + (long)(256 + hi * 256) * 256;
#pragma unroll
        for (int ni = 0; ni < 4; ni++) {
            int cn = wid * 64 + ni * 16 + l15;
            bfr[ni] = *(const bf16x8*)(Wb + (long)cn * 256 + innerk);
        }
#pragma unroll
        for (int mi = 0; mi < MT; mi++)
#pragma unroll
            for (int ni = 0; ni < 4; ni++)
                acc[mi][ni] = __builtin_amdgcn_mfma_f32_16x16x32_bf16(af[mi], bfr[ni],
                                                                     acc[mi][ni], 0, 0, 0);
    }

    float cv[4], gv[4], bv[4];
#pragma unroll
    for (int ni = 0; ni < 4; ni++) {
        int c = wid * 64 + ni * 16 + l15;
        cv[ni] = carr_d[c];
        gv[ni] = gamma[c];
        bv[ni] = beta[c];
    }

#pragma unroll
    for (int mi = 0; mi < MT; mi++) {
#pragma unroll
        for (int r = 0; r < 4; r++) {
            int row = mi * 16 + l4 * 4 + r;
            int nid = s_nid[row];
            float s = 0.f, s2 = 0.f;
#pragma unroll
            for (int ni = 0; ni < 4; ni++) {
                int c = wid * 64 + ni * 16 + l15;
                float h = acc[mi][ni][r] + T0[(long)nid * 256 + c] + cv[ni];
                h = fmaxf(h, 0.f);
                acc[mi][ni][r] = h;
                s += h;
                s2 += h * h;
            }
#pragma unroll
            for (int m = 1; m < 16; m <<= 1) {
                s += __shfl_xor(s, m);
                s2 += __shfl_xor(s2, m);
            }
            if (l15 == 0) {
                s_part[wid][row][0] = s;
                s_part[wid][row][1] = s2;
            }
        }
    }
    __syncthreads();

#pragma unroll
    for (int mi = 0; mi < MT; mi++) {
#pragma unroll
        for (int r = 0; r < 4; r++) {
            int row = mi * 16 + l4 * 4 + r;
            float s = s_part[0][row][0] + s_part[1][row][0] + s_part[2][row][0] + s_part[3][row][0];
            float s2 = s_part[0][row][1] + s_part[1][row][1] + s_part[2][row][1] + s_part[3][row][1];
            float mu = s * (1.f / 256.f);
            float rs = rsqrtf(s2 * (1.f / 256.f) - mu * mu + 1e-5f);
            unsigned short* o = ebuf_out + ((long)b * n + row0 + row) * 256;
#pragma unroll
            for (int ni = 0; ni < 4; ni++) {
                int c = wid * 64 + ni * 16 + l15;
                o[c] = f2bf((acc[mi][ni][r] - mu) * rs * gv[ni] + bv[ni]);
            }
        }
    }
}

// ---------------- Subtree tail: levels 7..1. 16 blocks (block = (batch, half)), 512 threads,
// 8 waves x 32 cols. B (WTbf) in registers (breg); amdgpu_waves_per_eu(2,2) lifts the
// 128-VGPR cap (verified R9: k_tail left the top-5).
__global__ __attribute__((amdgpu_waves_per_eu(2, 2))) __launch_bounds__(512)
void k_tail(const unsigned short* __restrict__ prev,
            const int* __restrict__ op_ids,
            const float* __restrict__ T0,
            const float* __restrict__ carr,
            const float* __restrict__ gamma,
            const float* __restrict__ beta,
            const unsigned short* __restrict__ WTbf,
            unsigned short* __restrict__ mid) {
    __shared__ unsigned short sA[64 * 256];
    __shared__ unsigned short sB[64 * 256];
    __shared__ int s_nid_all[255];
    __shared__ float s_part[8][64][2];
    int b = blockIdx.x >> 1;
    int h = blockIdx.x & 1;
    int t = threadIdx.x;
    int wid = t >> 6, lane = t & 63;
    int l15 = lane & 15, l4 = lane >> 4;

    // B fragments for this wave's 32 cols, ALL 16 ksteps, held in registers across levels
    bf16x8 breg[16][2];
#pragma unroll
    for (int kk = 0; kk < 16; kk++) {
        int k0 = kk * 32 + l4 * 8;
        int hi = k0 >> 8;
        int innerk = k0 & 255;
        const unsigned short* Wb = WTbf + (long)(256 + hi * 256) * 256;
#pragma unroll
        for (int ni = 0; ni < 2; ni++) {
            int cn = wid * 32 + ni * 16 + l15;
            breg[kk][ni] = *(const bf16x8*)(Wb + (long)cn * 256 + innerk);
        }
    }

    if (t < 255) s_nid_all[t] = op_ids[b * 16383 + t];
    float gv[2], bv[2];
#pragma unroll
    for (int ni = 0; ni < 2; ni++) {
        int c = wid * 32 + ni * 16 + l15;
        gv[ni] = gamma[c];
        bv[ni] = beta[c];
    }
    __syncthreads();

    unsigned short* cur = sA;
    unsigned short* nxt = sB;

    // ---- Level 7: 64 local rows (global level-7 nodes h*64 + [0,64)) from global X -> sA
    {
        const unsigned short* X = prev + ((long)b * 256 + h * 128) * 256;
        const float* carr7 = carr + 7 * 256;
        float cv7[2];
#pragma unroll
        for (int ni = 0; ni < 2; ni++) cv7[ni] = carr7[wid * 32 + ni * 16 + l15];

        float tv[4][4][2];
#pragma unroll
        for (int mi = 0; mi < 4; mi++)
#pragma unroll
            for (int r = 0; r < 4; r++) {
                int row = mi * 16 + l4 * 4 + r;
                int nid = s_nid_all[127 + h * 64 + row];
#pragma unroll
                for (int ni = 0; ni < 2; ni++)
                    tv[mi][r][ni] = T0[(long)nid * 256 + wid * 32 + ni * 16 + l15];
            }

        f32x4 acc[4][2] = {};
#pragma unroll
        for (int kk = 0; kk < 16; kk++) {
            int k0 = kk * 32 + l4 * 8;
            bf16x8 af[4];
#pragma unroll
            for (int mi = 0; mi < 4; mi++)
                af[mi] = *(const bf16x8*)(X + (long)(mi * 16 + l15) * 512 + k0);
#pragma unroll
            for (int mi = 0; mi < 4; mi++)
#pragma unroll
                for (int ni = 0; ni < 2; ni++)
                    acc[mi][ni] = __builtin_amdgcn_mfma_f32_16x16x32_bf16(af[mi], breg[kk][ni],
                                                                         acc[mi][ni], 0, 0, 0);
        }

#pragma unroll
        for (int mi = 0; mi < 4; mi++)
#pragma unroll
            for (int r = 0; r < 4; r++) {
                float s = 0.f, s2 = 0.f;
#pragma unroll
                for (int ni = 0; ni < 2; ni++) {
                    float hh = fmaxf(acc[mi][ni][r] + tv[mi][r][ni] + cv7[ni], 0.f);
                    acc[mi][ni][r] = hh;
                    s += hh;
                    s2 += hh * hh;
                }
#pragma unroll
                for (int m = 1; m < 16; m <<= 1) {
                    s += __shfl_xor(s, m);
                    s2 += __shfl_xor(s2, m);
                }
                if (l15 == 0) {
                    int row = mi * 16 + l4 * 4 + r;
                    s_part[wid][row][0] = s;
                    s_part[wid][row][1] = s2;
                }
            }
        __syncthreads();

#pragma unroll
        for (int mi = 0; mi < 4; mi++)
#pragma unroll
            for (int r = 0; r < 4; r++) {
                int row = mi * 16 + l4 * 4 + r;
                float s = 0.f, s2 = 0.f;
#pragma unroll
                for (int w = 0; w < 8; w++) {
                    s += s_part[w][row][0];
                    s2 += s_part[w][row][1];
                }
                float mu = s * (1.f / 256.f);
                float rs = rsqrtf(s2 * (1.f / 256.f) - mu * mu + 1e-5f);
#pragma unroll
                for (int ni = 0; ni < 2; ni++) {
                    int c = wid * 32 + ni * 16 + l15;
                    unsigned short val = f2bf((acc[mi][ni][r] - mu) * rs * gv[ni] + bv[ni]);
                    *(unsigned short*)((char*)sA + row * 512 +
                                       ((c * 2) ^ (((row >> 1) & 7) << 4))) = val;
                }
            }
        __syncthreads();
    }

    // ---- Levels 6..1: m = 2^(ld-1) local rows; LDS ping-pong; ld==1 writes mid
    for (int ld = 6; ld >= 1; ld--) {
        int ng = 1 << ld;   // global nodes at this level
        int m = ng >> 1;    // local rows (this subtree half)
        int mtiles = (m + 15) >> 4;

        float tv[2][4][2];
#pragma unroll
        for (int mi = 0; mi < 2; mi++)
            if (mi < mtiles)
#pragma unroll
                for (int r = 0; r < 4; r++) {
                    int row = mi * 16 + l4 * 4 + r;
                    int rc = row < m ? row : m - 1;
                    int nid = s_nid_all[(ng - 1) + h * m + rc];
#pragma unroll
                    for (int ni = 0; ni < 2; ni++)
                        tv[mi][r][ni] = T0[(long)nid * 256 + wid * 32 + ni * 16 + l15];
                }

        f32x4 acc[2][2] = {};
#pragma unroll
        for (int kk = 0; kk < 16; kk++) {
            int k0 = kk * 32 + l4 * 8;
            int hi = k0 >> 8;
            int innerk = k0 & 255;
            int binr = innerk * 2;
            bf16x8 af[2];
#pragma unroll
            for (int mi = 0; mi < 2; mi++)
                if (mi < mtiles) {
                    int node = 2 * (mi * 16 + l15) + hi;
                    af[mi] = *(const bf16x8*)((const char*)cur + node * 512 +
                                              (binr ^ (((node >> 1) & 7) << 4)));
                }
#pragma unroll
            for (int mi = 0; mi < 2; mi++)
                if (mi < mtiles)
#pragma unroll
                    for (int ni = 0; ni < 2; ni++)
                        acc[mi][ni] = __builtin_amdgcn_mfma_f32_16x16x32_bf16(af[mi], breg[kk][ni],
                                                                             acc[mi][ni], 0, 0, 0);
        }

        const float* carr_d = carr + ld * 256;
        float cv[2];
#pragma unroll
        for (int ni = 0; ni < 2; ni++) cv[ni] = carr_d[wid * 32 + ni * 16 + l15];

#pragma unroll
        for (int mi = 0; mi < 2; mi++)
            if (mi < mtiles)
#pragma unroll
                for (int r = 0; r < 4; r++) {
                    float s = 0.f, s2 = 0.f;
#pragma unroll
                    for (int ni = 0; ni < 2; ni++) {
                        float hh = fmaxf(acc[mi][ni][r] + tv[mi][r][ni] + cv[ni], 0.f);
                        acc[mi][ni][r] = hh;
                        s += hh;
                        s2 += hh * hh;
                    }
#pragma unroll
                    for (int m2 = 1; m2 < 16; m2 <<= 1) {
                        s += __shfl_xor(s, m2);
                        s2 += __shfl_xor(s2, m2);
                    }
                    if (l15 == 0) {
                        int row = mi * 16 + l4 * 4 + r;
                        s_part[wid][row][0] = s;
                        s_part[wid][row][1] = s2;
                    }
                }
        __syncthreads();

#pragma unroll
        for (int mi = 0; mi < 2; mi++)
            if (mi < mtiles)
#pragma unroll
                for (int r = 0; r < 4; r++) {
                    int row = mi * 16 + l4 * 4 + r;
                    if (row < m) {
                        float s = 0.f, s2 = 0.f;
#pragma unroll
                        for (int w = 0; w < 8; w++) {
                            s += s_part[w][row][0];
                            s2 += s_part[w][row][1];
                        }
                        float mu = s * (1.f / 256.f);
                        float rs = rsqrtf(s2 * (1.f / 256.f) - mu * mu + 1e-5f);
#pragma unroll
                        for (int ni = 0; ni < 2; ni++) {
                            int c = wid * 32 + ni * 16 + l15;
                            float val = (acc[mi][ni][r] - mu) * rs * gv[ni] + bv[ni];
                            if (ld == 1) {
                                mid[(long)(b * 2 + h) * 256 + c] = f2bf(val);
                            } else {
                                *(unsigned short*)((char*)nxt + row * 512 +
                                                   ((c * 2) ^ (((row >> 1) & 7) << 4))) = f2bf(val);
                            }
                        }
                    }
                }
        __syncthreads();
        unsigned short* tmp = cur;
        cur = nxt;
        nxt = tmp;
    }
}

// ---------------- Root (level 0): one block, 4 waves. GEMM 8 rows (batches) x K=512 x N=256.
__global__ __launch_bounds__(256) void k_root(const unsigned short* __restrict__ mid,
                                              const int* __restrict__ op_ids,
                                              const float* __restrict__ T0,
                                              const float* __restrict__ carr,
                                              const float* __restrict__ gamma,
                                              const float* __restrict__ beta,
                                              const unsigned short* __restrict__ WTbf,
                                              float* __restrict__ out) {
    __shared__ float s_part[4][16][2];
    int t = threadIdx.x;
    int wid = t >> 6, lane = t & 63;
    int l15 = lane & 15, l4 = lane >> 4;

    f32x4 acc[4] = {};
    for (int kk = 0; kk < 16; kk++) {
        int k0 = kk * 32 + l4 * 8;
        int hi = k0 >> 8;
        int innerk = k0 & 255;
        int arow = l15 & 7;  // rows 8..15 mirror 0..7; their outputs are discarded
        bf16x8 af = *(const bf16x8*)(mid + (long)arow * 512 + k0);
        const unsigned short* Wb = WTbf + (long)(256 + hi * 256) * 256;
#pragma unroll
        for (int ni = 0; ni < 4; ni++) {
            int cn = wid * 64 + ni * 16 + l15;
            bf16x8 bfr = *(const bf16x8*)(Wb + (long)cn * 256 + innerk);
            acc[ni] = __builtin_amdgcn_mfma_f32_16x16x32_bf16(af, bfr, acc[ni], 0, 0, 0);
        }
    }

    float cv[4], gv[4], bv[4], tvx[4][4];
#pragma unroll
    for (int ni = 0; ni < 4; ni++) {
        int c = wid * 64 + ni * 16 + l15;
        cv[ni] = carr[c];
        gv[ni] = gamma[c];
        bv[ni] = beta[c];
    }
#pragma unroll
    for (int r = 0; r < 4; r++) {
        int row = l4 * 4 + r;
        int bb = row & 7;
        int nid = op_ids[bb * 16383];
#pragma unroll
        for (int ni = 0; ni < 4; ni++)
            tvx[r][ni] = T0[(long)nid * 256 + wid * 64 + ni * 16 + l15];
    }

#pragma unroll
    for (int r = 0; r < 4; r++) {
        int row = l4 * 4 + r;
        float s = 0.f, s2 = 0.f;
#pragma unroll
        for (int ni = 0; ni < 4; ni++) {
            float hh = fmaxf(acc[ni][r] + tvx[r][ni] + cv[ni], 0.f);
            acc[ni][r] = hh;
            s += hh;
            s2 += hh * hh;
        }
#pragma unroll
        for (int m = 1; m < 16; m <<= 1) {
            s += __shfl_xor(s, m);
            s2 += __shfl_xor(s2, m);
        }
        if (l15 == 0) {
            s_part[wid][row][0] = s;
            s_part[wid][row][1] = s2;
        }
    }
    __syncthreads();

#pragma unroll
    for (int r = 0; r < 4; r++) {
        int row = l4 * 4 + r;
        if (row < 8) {
            float s = s_part[0][row][0] + s_part[1][row][0] + s_part[2][row][0] + s_part[3][row][0];
            float s2 = s_part[0][row][1] + s_part[1][row][1] + s_part[2][row][1] + s_part[3][row][1];
            float mu = s * (1.f / 256.f);
            float rs = rsqrtf(s2 * (1.f / 256.f) - mu * mu + 1e-5f);
#pragma unroll
            for (int ni = 0; ni < 4; ni++) {
                int c = wid * 64 + ni * 16 + l15;
                out[row * 256 + c] = (acc[ni][r] - mu) * rs * gv[ni] + bv[ni];
            }
        }
    }
}

extern "C" void kernel_launch(void* const* d_in, const int* in_sizes, int n_in,
                              void* d_out, int out_size, void* d_ws, size_t ws_size,
                              hipStream_t stream) {
    const int* leaf_ids = (const int*)d_in[0];
    const int* op_ids = (const int*)d_in[1];
    const float* tok = (const float*)d_in[2];
    const float* dep = (const float*)d_in[3];
    const float* idx = (const float*)d_in[4];
    const float* W = (const float*)d_in[5];
    const float* bvec = (const float*)d_in[6];
    const float* gamma = (const float*)d_in[7];
    const float* beta = (const float*)d_in[8];
    float* out = (float*)d_out;

    char* ws = (char*)d_ws;
    float* T = (float*)(ws);                                             // 3 MB (T0|T1|T2)
    unsigned short* WTbf = (unsigned short*)(ws + 3u * 1024 * 1024);     // 384 KB
    unsigned short* tokbf = (unsigned short*)(ws + 3u * 1024 * 1024 + 512 * 1024);  // 512 KB
    float* carr = (float*)(ws + 4u * 1024 * 1024 + 64 * 1024);           // 14 KB
    unsigned short* mid = (unsigned short*)(ws + 6u * 1024 * 1024);      // 8 KB
    unsigned short* ebufA = (unsigned short*)(ws + 8u * 1024 * 1024);    // 16 MB
    unsigned short* ebufB = (unsigned short*)(ws + 40u * 1024 * 1024);   // 8 MB

    k_prep<<<318, 256, 0, stream>>>(tok, W, dep, idx, bvec, tokbf, WTbf, carr);
    k_ttmm<<<dim3(32, 3), 256, 0, stream>>>(tokbf, WTbf, T);

    // levels 13+12 -> ebufA (4096 rows/batch), 32 rows/block
    k_level12f<<<dim3(128, 8), 256, 0, stream>>>(leaf_ids, op_ids, T, carr, gamma, beta, WTbf,
                                                 ebufA);
    // level 11 -> ebufB (2048 rows/batch)
    k_level<4><<<dim3(32, 8), 256, 0, stream>>>(ebufA, ebufB, op_ids, T, carr + 11 * 256, gamma,
                                                beta, WTbf, 2048);
    // level 10 -> ebufA (1024 rows/batch)
    k_level<2><<<dim3(32, 8), 256, 0, stream>>>(ebufB, ebufA, op_ids, T, carr + 10 * 256, gamma,
                                                beta, WTbf, 1024);
    // level 9 -> ebufB (512 rows/batch)
    k_level<2><<<dim3(16, 8), 256, 0, stream>>>(ebufA, ebufB, op_ids, T, carr + 9 * 256, gamma,
                                                beta, WTbf, 512);
    // level 8 -> ebufA (256 rows/batch)
    k_level<2><<<dim3(8, 8), 256, 0, stream>>>(ebufB, ebufA, op_ids, T, carr + 8 * 256, gamma,
                                               beta, WTbf, 256);
    // levels 7..1 (16 blocks: batch x subtree-half) -> mid
    k_tail<<<16, 512, 0, stream>>>(ebufA, op_ids, T, carr, gamma, beta, WTbf, mid);
    // level 0
    k_root<<<1, 256, 0, stream>>>(mid, op_ids, T, carr, gamma, beta, WTbf, out);
}

// Round 11
// 237.369 us; speedup vs baseline: 1.5124x; 1.2031x over previous
//
#include <hip/hip_runtime.h>

typedef float f32x4 __attribute__((ext_vector_type(4)));
typedef short bf16x8 __attribute__((ext_vector_type(8)));

__device__ inline unsigned short f2bf(float f) {
    unsigned int u = __builtin_bit_cast(unsigned int, f);
    unsigned int r = (u + 0x7FFFu + ((u >> 16) & 1u)) >> 16;
    return (unsigned short)r;
}

// ---------------- Combined prep: tok->bf16 | W transpose->bf16 | carr split-K partials
__global__ __launch_bounds__(256) void k_prep(const float* __restrict__ tok,
                                              const float* __restrict__ W,
                                              const float* __restrict__ dep,
                                              const float* __restrict__ idx,
                                              const float* __restrict__ bvec,
                                              unsigned short* __restrict__ tokbf,
                                              unsigned short* __restrict__ WTbf,
                                              float* __restrict__ carrp) {
    __shared__ float s_tile[64][65];
    int bx = blockIdx.x;
    if (bx < 256) {
        int i = bx * 256 + threadIdx.x;
        const float4 v = *(const float4*)(tok + (long)i * 4);
        ushort4 o;
        o.x = f2bf(v.x); o.y = f2bf(v.y); o.z = f2bf(v.z); o.w = f2bf(v.w);
        *(ushort4*)(tokbf + (long)i * 4) = o;
    } else if (bx < 304) {
        int bb = bx - 256;
        int sec = bb >> 4;
        int tt = bb & 15;
        int k0 = (tt >> 2) * 64, j0 = (tt & 3) * 64;
        int tx = threadIdx.x & 63, ty = threadIdx.x >> 6;
#pragma unroll
        for (int r = 0; r < 16; r++) {
            int kk = ty * 16 + r;
            s_tile[kk][tx] = W[(sec * 256 + k0 + kk) * 256 + j0 + tx];
        }
        __syncthreads();
#pragma unroll
        for (int r = 0; r < 16; r++) {
            int jj = ty * 16 + r;
            WTbf[(sec * 256 + j0 + jj) * 256 + k0 + tx] = f2bf(s_tile[tx][jj]);
        }
    } else {
        // carr split-K: 112 blocks = 14 d x 8 chunks of 32 k's
        int q = bx - 304;
        int d = q >> 3;
        int c = q & 7;
        int j = threadIdx.x;
        float acc = (c == 0) ? bvec[j] : 0.f;
        int kbeg = c * 32, kend = kbeg + 32;
#pragma unroll 4
        for (int k = kbeg; k < kend; k++) {
            float dv = dep[(d + 1) * 256 + k];
            acc += dv * (W[(768 + k) * 256 + j] + W[(1280 + k) * 256 + j]);
            acc += idx[k] * W[(1024 + k) * 256 + j];
            acc += idx[256 + k] * W[(1536 + k) * 256 + j];
        }
        if (d == 13) {
#pragma unroll 4
            for (int k = kbeg; k < kend; k++) {
                float dv = dep[14 * 256 + k];
                acc += dv * (W[(256 + k) * 256 + j] + W[(512 + k) * 256 + j]);
            }
        }
        carrp[(long)q * 256 + j] = acc;
    }
}

// ---------------- carr reduce: carr[d][j] = sum over 8 chunks
__global__ __launch_bounds__(256) void k_carrsum(const float* __restrict__ carrp,
                                                 float* __restrict__ carr) {
    int d = blockIdx.x;
    int j = threadIdx.x;
    float s = 0.f;
#pragma unroll
    for (int c = 0; c < 8; c++) s += carrp[(long)(d * 8 + c) * 256 + j];
    carr[d * 256 + j] = s;
}

// ---------------- T tables via MFMA: T[sec][1024][256] = tokbf @ Wsec
__global__ __launch_bounds__(256) void k_ttmm(const unsigned short* __restrict__ tokbf,
                                              const unsigned short* __restrict__ WTbf,
                                              float* __restrict__ T) {
    int wid = threadIdx.x >> 6, lane = threadIdx.x & 63;
    int l15 = lane & 15, l4 = lane >> 4;
    int row0 = blockIdx.x * 32;
    int sec = blockIdx.y;

    f32x4 acc[2][4] = {};
    for (int kk = 0; kk < 8; kk++) {
        int k0 = kk * 32 + l4 * 8;
        bf16x8 af[2], bfr[4];
#pragma unroll
        for (int mi = 0; mi < 2; mi++)
            af[mi] = *(const bf16x8*)(tokbf + (long)(row0 + mi * 16 + l15) * 256 + k0);
#pragma unroll
        for (int ni = 0; ni < 4; ni++)
            bfr[ni] = *(const bf16x8*)(WTbf + (long)(sec * 256 + wid * 64 + ni * 16 + l15) * 256 + k0);
#pragma unroll
        for (int mi = 0; mi < 2; mi++)
#pragma unroll
            for (int ni = 0; ni < 4; ni++)
                acc[mi][ni] = __builtin_amdgcn_mfma_f32_16x16x32_bf16(af[mi], bfr[ni],
                                                                     acc[mi][ni], 0, 0, 0);
    }
#pragma unroll
    for (int mi = 0; mi < 2; mi++)
#pragma unroll
        for (int r = 0; r < 4; r++) {
            int row = row0 + mi * 16 + l4 * 4 + r;
#pragma unroll
            for (int ni = 0; ni < 4; ni++) {
                int c = wid * 64 + ni * 16 + l15;
                T[(long)sec * 262144 + (long)row * 256 + c] = acc[mi][ni][r];
            }
        }
}

// ---------------- Fused level 13+12: 32 rows / 64 nodes per block
__global__ __launch_bounds__(256) void k_level12f(const int* __restrict__ leaf_ids,
                                                  const int* __restrict__ op_ids,
                                                  const float* __restrict__ T,
                                                  const float* __restrict__ carr,
                                                  const float* __restrict__ gamma,
                                                  const float* __restrict__ beta,
                                                  const unsigned short* __restrict__ WTbf,
                                                  unsigned short* __restrict__ ebuf_out) {
    __shared__ unsigned short sA[64 * 256];
    __shared__ int s_nid13[64];
    __shared__ int s_leaf[128];
    __shared__ int s_nid[32];
    __shared__ float s_part[4][32][2];
    int b = blockIdx.y;
    int row0 = blockIdx.x * 32;
    int t = threadIdx.x;
    int wid = t >> 6, lane = t & 63;
    int l15 = lane & 15, l4 = lane >> 4;
    const float* T0 = T;
    const float* T1 = T + 262144;
    const float* T2 = T + 524288;

    if (t < 64) s_nid13[t] = op_ids[b * 16383 + 8191 + 2 * row0 + t];
    if (t < 128) s_leaf[t] = leaf_ids[b * 16384 + 4 * row0 + t];
    if (t < 32) s_nid[t] = op_ids[b * 16383 + 4095 + row0 + t];
    __syncthreads();

    {
        const float* c13 = carr + 13 * 256;
        float4 dd = *(const float4*)(c13 + 4 * lane);
        float4 g4 = *(const float4*)(gamma + 4 * lane);
        float4 b4 = *(const float4*)(beta + 4 * lane);
#pragma unroll 4
        for (int j = 0; j < 16; j++) {
            int node = wid * 16 + j;
            int nid = s_nid13[node];
            int ll = s_leaf[2 * node], lr = s_leaf[2 * node + 1];
            float4 a = *(const float4*)(T0 + (long)nid * 256 + 4 * lane);
            float4 bb = *(const float4*)(T1 + (long)ll * 256 + 4 * lane);
            float4 cc = *(const float4*)(T2 + (long)lr * 256 + 4 * lane);
            float v0 = fmaxf(a.x + bb.x + cc.x + dd.x, 0.f);
            float v1 = fmaxf(a.y + bb.y + cc.y + dd.y, 0.f);
            float v2 = fmaxf(a.z + bb.z + cc.z + dd.z, 0.f);
            float v3 = fmaxf(a.w + bb.w + cc.w + dd.w, 0.f);
            float s = v0 + v1 + v2 + v3;
            float s2 = v0 * v0 + v1 * v1 + v2 * v2 + v3 * v3;
#pragma unroll
            for (int m = 1; m < 64; m <<= 1) {
                s += __shfl_xor(s, m);
                s2 += __shfl_xor(s2, m);
            }
            float mu = s * (1.f / 256.f);
            float rs = rsqrtf(s2 * (1.f / 256.f) - mu * mu + 1e-5f);
            ushort4 o;
            o.x = f2bf((v0 - mu) * rs * g4.x + b4.x);
            o.y = f2bf((v1 - mu) * rs * g4.y + b4.y);
            o.z = f2bf((v2 - mu) * rs * g4.z + b4.z);
            o.w = f2bf((v3 - mu) * rs * g4.w + b4.w);
            *(ushort4*)((char*)sA + node * 512 + ((8 * lane) ^ (((node >> 1) & 7) << 4))) = o;
        }
    }
    __syncthreads();

    f32x4 acc[2][4] = {};
    for (int kk = 0; kk < 16; kk++) {
        int k0 = kk * 32 + l4 * 8;
        int hi = k0 >> 8;
        int binr = (k0 & 255) * 2;
        bf16x8 af[2], bfr[4];
#pragma unroll
        for (int mi = 0; mi < 2; mi++) {
            int node = 2 * (mi * 16 + l15) + hi;
            af[mi] = *(const bf16x8*)((const char*)sA + node * 512 + (binr ^ (((node >> 1) & 7) << 4)));
        }
        const unsigned short* Wb = WTbf + (long)(256 + hi * 256) * 256;
        int innerk = k0 & 255;
#pragma unroll
        for (int ni = 0; ni < 4; ni++) {
            int cn = wid * 64 + ni * 16 + l15;
            bfr[ni] = *(const bf16x8*)(Wb + (long)cn * 256 + innerk);
        }
#pragma unroll
        for (int mi = 0; mi < 2; mi++)
#pragma unroll
            for (int ni = 0; ni < 4; ni++)
                acc[mi][ni] = __builtin_amdgcn_mfma_f32_16x16x32_bf16(af[mi], bfr[ni],
                                                                     acc[mi][ni], 0, 0, 0);
    }

    const float* carr_d = carr + 12 * 256;
    float cv[4], gv[4], bv[4];
#pragma unroll
    for (int ni = 0; ni < 4; ni++) {
        int c = wid * 64 + ni * 16 + l15;
        cv[ni] = carr_d[c];
        gv[ni] = gamma[c];
        bv[ni] = beta[c];
    }

#pragma unroll
    for (int mi = 0; mi < 2; mi++) {
#pragma unroll
        for (int r = 0; r < 4; r++) {
            int row = mi * 16 + l4 * 4 + r;
            int nid = s_nid[row];
            float s = 0.f, s2 = 0.f;
#pragma unroll
            for (int ni = 0; ni < 4; ni++) {
                int c = wid * 64 + ni * 16 + l15;
                float h = acc[mi][ni][r] + T0[(long)nid * 256 + c] + cv[ni];
                h = fmaxf(h, 0.f);
                acc[mi][ni][r] = h;
                s += h;
                s2 += h * h;
            }
#pragma unroll
            for (int m = 1; m < 16; m <<= 1) {
                s += __shfl_xor(s, m);
                s2 += __shfl_xor(s2, m);
            }
            if (l15 == 0) {
                s_part[wid][row][0] = s;
                s_part[wid][row][1] = s2;
            }
        }
    }
    __syncthreads();

#pragma unroll
    for (int mi = 0; mi < 2; mi++) {
#pragma unroll
        for (int r = 0; r < 4; r++) {
            int row = mi * 16 + l4 * 4 + r;
            float s = s_part[0][row][0] + s_part[1][row][0] + s_part[2][row][0] + s_part[3][row][0];
            float s2 = s_part[0][row][1] + s_part[1][row][1] + s_part[2][row][1] + s_part[3][row][1];
            float mu = s * (1.f / 256.f);
            float rs = rsqrtf(s2 * (1.f / 256.f) - mu * mu + 1e-5f);
            unsigned short* o = ebuf_out + ((long)b * 4096 + row0 + row) * 256;
#pragma unroll
            for (int ni = 0; ni < 4; ni++) {
                int c = wid * 64 + ni * 16 + l15;
                o[c] = f2bf((acc[mi][ni][r] - mu) * rs * gv[ni] + bv[ni]);
            }
        }
    }
}

// ---------------- Levels 11..8: MFMA GEMM + gather + relu + LN (MT*16 rows per block)
template <int MT>
__global__ __launch_bounds__(256) void k_level(const unsigned short* __restrict__ ebuf_prev,
                                               unsigned short* __restrict__ ebuf_out,
                                               const int* __restrict__ op_ids,
                                               const float* __restrict__ T0,
                                               const float* __restrict__ carr_d,
                                               const float* __restrict__ gamma,
                                               const float* __restrict__ beta,
                                               const unsigned short* __restrict__ WTbf,
                                               int n) {
    int wid = threadIdx.x >> 6, lane = threadIdx.x & 63;
    int b = blockIdx.y;
    int row0 = blockIdx.x * (MT * 16);
    int l15 = lane & 15, l4 = lane >> 4;

    __shared__ int s_nid[MT * 16];
    __shared__ float s_part[4][MT * 16][2];

    if (threadIdx.x < MT * 16)
        s_nid[threadIdx.x] = op_ids[b * 16383 + (n - 1) + row0 + threadIdx.x];
    __syncthreads();

    const unsigned short* X = ebuf_prev + (long)b * (2 * (long)n) * 256;

    f32x4 acc[MT][4] = {};

    for (int kk = 0; kk < 16; kk++) {
        int k0 = kk * 32 + l4 * 8;
        int hi = k0 >> 8;
        int innerk = k0 & 255;
        bf16x8 af[MT], bfr[4];
#pragma unroll
        for (int mi = 0; mi < MT; mi++) {
            int r = row0 + mi * 16 + l15;
            af[mi] = *(const bf16x8*)(X + (long)r * 512 + k0);
        }
        const unsigned short* Wb = WTbf + (long)(256 + hi * 256) * 256;
#pragma unroll
        for (int ni = 0; ni < 4; ni++) {
            int cn = wid * 64 + ni * 16 + l15;
            bfr[ni] = *(const bf16x8*)(Wb + (long)cn * 256 + innerk);
        }
#pragma unroll
        for (int mi = 0; mi < MT; mi++)
#pragma unroll
            for (int ni = 0; ni < 4; ni++)
                acc[mi][ni] = __builtin_amdgcn_mfma_f32_16x16x32_bf16(af[mi], bfr[ni],
                                                                     acc[mi][ni], 0, 0, 0);
    }

    float cv[4], gv[4], bv[4];
#pragma unroll
    for (int ni = 0; ni < 4; ni++) {
        int c = wid * 64 + ni * 16 + l15;
        cv[ni] = carr_d[c];
        gv[ni] = gamma[c];
        bv[ni] = beta[c];
    }

#pragma unroll
    for (int mi = 0; mi < MT; mi++) {
#pragma unroll
        for (int r = 0; r < 4; r++) {
            int row = mi * 16 + l4 * 4 + r;
            int nid = s_nid[row];
            float s = 0.f, s2 = 0.f;
#pragma unroll
            for (int ni = 0; ni < 4; ni++) {
                int c = wid * 64 + ni * 16 + l15;
                float h = acc[mi][ni][r] + T0[(long)nid * 256 + c] + cv[ni];
                h = fmaxf(h, 0.f);
                acc[mi][ni][r] = h;
                s += h;
                s2 += h * h;
            }
#pragma unroll
            for (int m = 1; m < 16; m <<= 1) {
                s += __shfl_xor(s, m);
                s2 += __shfl_xor(s2, m);
            }
            if (l15 == 0) {
                s_part[wid][row][0] = s;
                s_part[wid][row][1] = s2;
            }
        }
    }
    __syncthreads();

#pragma unroll
    for (int mi = 0; mi < MT; mi++) {
#pragma unroll
        for (int r = 0; r < 4; r++) {
            int row = mi * 16 + l4 * 4 + r;
            float s = s_part[0][row][0] + s_part[1][row][0] + s_part[2][row][0] + s_part[3][row][0];
            float s2 = s_part[0][row][1] + s_part[1][row][1] + s_part[2][row][1] + s_part[3][row][1];
            float mu = s * (1.f / 256.f);
            float rs = rsqrtf(s2 * (1.f / 256.f) - mu * mu + 1e-5f);
            unsigned short* o = ebuf_out + ((long)b * n + row0 + row) * 256;
#pragma unroll
            for (int ni = 0; ni < 4; ni++) {
                int c = wid * 64 + ni * 16 + l15;
                o[c] = f2bf((acc[mi][ni][r] - mu) * rs * gv[ni] + bv[ni]);
            }
        }
    }
}

// ---------------- Subtree tail: levels 7..1. 16 blocks (block = (batch, half)), 512 threads,
// 8 waves x 32 cols. B (WTbf) in registers (breg); amdgpu_waves_per_eu(2,2) lifts the
// 128-VGPR cap (verified R9).
__global__ __attribute__((amdgpu_waves_per_eu(2, 2))) __launch_bounds__(512)
void k_tail(const unsigned short* __restrict__ prev,
            const int* __restrict__ op_ids,
            const float* __restrict__ T0,
            const float* __restrict__ carr,
            const float* __restrict__ gamma,
            const float* __restrict__ beta,
            const unsigned short* __restrict__ WTbf,
            unsigned short* __restrict__ mid) {
    __shared__ unsigned short sA[64 * 256];
    __shared__ unsigned short sB[64 * 256];
    __shared__ int s_nid_all[255];
    __shared__ float s_part[8][64][2];
    int b = blockIdx.x >> 1;
    int h = blockIdx.x & 1;
    int t = threadIdx.x;
    int wid = t >> 6, lane = t & 63;
    int l15 = lane & 15, l4 = lane >> 4;

    bf16x8 breg[16][2];
#pragma unroll
    for (int kk = 0; kk < 16; kk++) {
        int k0 = kk * 32 + l4 * 8;
        int hi = k0 >> 8;
        int innerk = k0 & 255;
        const unsigned short* Wb = WTbf + (long)(256 + hi * 256) * 256;
#pragma unroll
        for (int ni = 0; ni < 2; ni++) {
            int cn = wid * 32 + ni * 16 + l15;
            breg[kk][ni] = *(const bf16x8*)(Wb + (long)cn * 256 + innerk);
        }
    }

    if (t < 255) s_nid_all[t] = op_ids[b * 16383 + t];
    float gv[2], bv[2];
#pragma unroll
    for (int ni = 0; ni < 2; ni++) {
        int c = wid * 32 + ni * 16 + l15;
        gv[ni] = gamma[c];
        bv[ni] = beta[c];
    }
    __syncthreads();

    unsigned short* cur = sA;
    unsigned short* nxt = sB;

    // ---- Level 7
    {
        const unsigned short* X = prev + ((long)b * 256 + h * 128) * 256;
        const float* carr7 = carr + 7 * 256;
        float cv7[2];
#pragma unroll
        for (int ni = 0; ni < 2; ni++) cv7[ni] = carr7[wid * 32 + ni * 16 + l15];

        float tv[4][4][2];
#pragma unroll
        for (int mi = 0; mi < 4; mi++)
#pragma unroll
            for (int r = 0; r < 4; r++) {
                int row = mi * 16 + l4 * 4 + r;
                int nid = s_nid_all[127 + h * 64 + row];
#pragma unroll
                for (int ni = 0; ni < 2; ni++)
                    tv[mi][r][ni] = T0[(long)nid * 256 + wid * 32 + ni * 16 + l15];
            }

        f32x4 acc[4][2] = {};
#pragma unroll
        for (int kk = 0; kk < 16; kk++) {
            int k0 = kk * 32 + l4 * 8;
            bf16x8 af[4];
#pragma unroll
            for (int mi = 0; mi < 4; mi++)
                af[mi] = *(const bf16x8*)(X + (long)(mi * 16 + l15) * 512 + k0);
#pragma unroll
            for (int mi = 0; mi < 4; mi++)
#pragma unroll
                for (int ni = 0; ni < 2; ni++)
                    acc[mi][ni] = __builtin_amdgcn_mfma_f32_16x16x32_bf16(af[mi], breg[kk][ni],
                                                                         acc[mi][ni], 0, 0, 0);
        }

#pragma unroll
        for (int mi = 0; mi < 4; mi++)
#pragma unroll
            for (int r = 0; r < 4; r++) {
                float s = 0.f, s2 = 0.f;
#pragma unroll
                for (int ni = 0; ni < 2; ni++) {
                    float hh = fmaxf(acc[mi][ni][r] + tv[mi][r][ni] + cv7[ni], 0.f);
                    acc[mi][ni][r] = hh;
                    s += hh;
                    s2 += hh * hh;
                }
#pragma unroll
                for (int m = 1; m < 16; m <<= 1) {
                    s += __shfl_xor(s, m);
                    s2 += __shfl_xor(s2, m);
                }
                if (l15 == 0) {
                    int row = mi * 16 + l4 * 4 + r;
                    s_part[wid][row][0] = s;
                    s_part[wid][row][1] = s2;
                }
            }
        __syncthreads();

#pragma unroll
        for (int mi = 0; mi < 4; mi++)
#pragma unroll
            for (int r = 0; r < 4; r++) {
                int row = mi * 16 + l4 * 4 + r;
                float s = 0.f, s2 = 0.f;
#pragma unroll
                for (int w = 0; w < 8; w++) {
                    s += s_part[w][row][0];
                    s2 += s_part[w][row][1];
                }
                float mu = s * (1.f / 256.f);
                float rs = rsqrtf(s2 * (1.f / 256.f) - mu * mu + 1e-5f);
#pragma unroll
                for (int ni = 0; ni < 2; ni++) {
                    int c = wid * 32 + ni * 16 + l15;
                    unsigned short val = f2bf((acc[mi][ni][r] - mu) * rs * gv[ni] + bv[ni]);
                    *(unsigned short*)((char*)sA + row * 512 +
                                       ((c * 2) ^ (((row >> 1) & 7) << 4))) = val;
                }
            }
        __syncthreads();
    }

    // ---- Levels 6..1
    for (int ld = 6; ld >= 1; ld--) {
        int ng = 1 << ld;
        int m = ng >> 1;
        int mtiles = (m + 15) >> 4;

        float tv[2][4][2];
#pragma unroll
        for (int mi = 0; mi < 2; mi++)
            if (mi < mtiles)
#pragma unroll
                for (int r = 0; r < 4; r++) {
                    int row = mi * 16 + l4 * 4 + r;
                    int rc = row < m ? row : m - 1;
                    int nid = s_nid_all[(ng - 1) + h * m + rc];
#pragma unroll
                    for (int ni = 0; ni < 2; ni++)
                        tv[mi][r][ni] = T0[(long)nid * 256 + wid * 32 + ni * 16 + l15];
                }

        f32x4 acc[2][2] = {};
#pragma unroll
        for (int kk = 0; kk < 16; kk++) {
            int k0 = kk * 32 + l4 * 8;
            int hi = k0 >> 8;
            int innerk = k0 & 255;
            int binr = innerk * 2;
            bf16x8 af[2];
#pragma unroll
            for (int mi = 0; mi < 2; mi++)
                if (mi < mtiles) {
                    int node = 2 * (mi * 16 + l15) + hi;
                    af[mi] = *(const bf16x8*)((const char*)cur + node * 512 +
                                              (binr ^ (((node >> 1) & 7) << 4)));
                }
#pragma unroll
            for (int mi = 0; mi < 2; mi++)
                if (mi < mtiles)
#pragma unroll
                    for (int ni = 0; ni < 2; ni++)
                        acc[mi][ni] = __builtin_amdgcn_mfma_f32_16x16x32_bf16(af[mi], breg[kk][ni],
                                                                             acc[mi][ni], 0, 0, 0);
        }

        const float* carr_d = carr + ld * 256;
        float cv[2];
#pragma unroll
        for (int ni = 0; ni < 2; ni++) cv[ni] = carr_d[wid * 32 + ni * 16 + l15];

#pragma unroll
        for (int mi = 0; mi < 2; mi++)
            if (mi < mtiles)
#pragma unroll
                for (int r = 0; r < 4; r++) {
                    float s = 0.f, s2 = 0.f;
#pragma unroll
                    for (int ni = 0; ni < 2; ni++) {
                        float hh = fmaxf(acc[mi][ni][r] + tv[mi][r][ni] + cv[ni], 0.f);
                        acc[mi][ni][r] = hh;
                        s += hh;
                        s2 += hh * hh;
                    }
#pragma unroll
                    for (int m2 = 1; m2 < 16; m2 <<= 1) {
                        s += __shfl_xor(s, m2);
                        s2 += __shfl_xor(s2, m2);
                    }
                    if (l15 == 0) {
                        int row = mi * 16 + l4 * 4 + r;
                        s_part[wid][row][0] = s;
                        s_part[wid][row][1] = s2;
                    }
                }
        __syncthreads();

#pragma unroll
        for (int mi = 0; mi < 2; mi++)
            if (mi < mtiles)
#pragma unroll
                for (int r = 0; r < 4; r++) {
                    int row = mi * 16 + l4 * 4 + r;
                    if (row < m) {
                        float s = 0.f, s2 = 0.f;
#pragma unroll
                        for (int w = 0; w < 8; w++) {
                            s += s_part[w][row][0];
                            s2 += s_part[w][row][1];
                        }
                        float mu = s * (1.f / 256.f);
                        float rs = rsqrtf(s2 * (1.f / 256.f) - mu * mu + 1e-5f);
#pragma unroll
                        for (int ni = 0; ni < 2; ni++) {
                            int c = wid * 32 + ni * 16 + l15;
                            float val = (acc[mi][ni][r] - mu) * rs * gv[ni] + bv[ni];
                            if (ld == 1) {
                                mid[(long)(b * 2 + h) * 256 + c] = f2bf(val);
                            } else {
                                *(unsigned short*)((char*)nxt + row * 512 +
                                                   ((c * 2) ^ (((row >> 1) & 7) << 4))) = f2bf(val);
                            }
                        }
                    }
                }
        __syncthreads();
        unsigned short* tmp = cur;
        cur = nxt;
        nxt = tmp;
    }
}

// ---------------- Root (level 0): one block, 4 waves. GEMM 8 rows x K=512 x N=256.
__global__ __launch_bounds__(256) void k_root(const unsigned short* __restrict__ mid,
                                              const int* __restrict__ op_ids,
                                              const float* __restrict__ T0,
                                              const float* __restrict__ carr,
                                              const float* __restrict__ gamma,
                                              const float* __restrict__ beta,
                                              const unsigned short* __restrict__ WTbf,
                                              float* __restrict__ out) {
    __shared__ float s_part[4][16][2];
    int t = threadIdx.x;
    int wid = t >> 6, lane = t & 63;
    int l15 = lane & 15, l4 = lane >> 4;

    f32x4 acc[4] = {};
    for (int kk = 0; kk < 16; kk++) {
        int k0 = kk * 32 + l4 * 8;
        int hi = k0 >> 8;
        int innerk = k0 & 255;
        int arow = l15 & 7;
        bf16x8 af = *(const bf16x8*)(mid + (long)arow * 512 + k0);
        const unsigned short* Wb = WTbf + (long)(256 + hi * 256) * 256;
#pragma unroll
        for (int ni = 0; ni < 4; ni++) {
            int cn = wid * 64 + ni * 16 + l15;
            bf16x8 bfr = *(const bf16x8*)(Wb + (long)cn * 256 + innerk);
            acc[ni] = __builtin_amdgcn_mfma_f32_16x16x32_bf16(af, bfr, acc[ni], 0, 0, 0);
        }
    }

    float cv[4], gv[4], bv[4], tvx[4][4];
#pragma unroll
    for (int ni = 0; ni < 4; ni++) {
        int c = wid * 64 + ni * 16 + l15;
        cv[ni] = carr[c];
        gv[ni] = gamma[c];
        bv[ni] = beta[c];
    }
#pragma unroll
    for (int r = 0; r < 4; r++) {
        int row = l4 * 4 + r;
        int bb = row & 7;
        int nid = op_ids[bb * 16383];
#pragma unroll
        for (int ni = 0; ni < 4; ni++)
            tvx[r][ni] = T0[(long)nid * 256 + wid * 64 + ni * 16 + l15];
    }

#pragma unroll
    for (int r = 0; r < 4; r++) {
        int row = l4 * 4 + r;
        float s = 0.f, s2 = 0.f;
#pragma unroll
        for (int ni = 0; ni < 4; ni++) {
            float hh = fmaxf(acc[ni][r] + tvx[r][ni] + cv[ni], 0.f);
            acc[ni][r] = hh;
            s += hh;
            s2 += hh * hh;
        }
#pragma unroll
        for (int m = 1; m < 16; m <<= 1) {
            s += __shfl_xor(s, m);
            s2 += __shfl_xor(s2, m);
        }
        if (l15 == 0) {
            s_part[wid][row][0] = s;
            s_part[wid][row][1] = s2;
        }
    }
    __syncthreads();

#pragma unroll
    for (int r = 0; r < 4; r++) {
        int row = l4 * 4 + r;
        if (row < 8) {
            float s = s_part[0][row][0] + s_part[1][row][0] + s_part[2][row][0] + s_part[3][row][0];
            float s2 = s_part[0][row][1] + s_part[1][row][1] + s_part[2][row][1] + s_part[3][row][1];
            float mu = s * (1.f / 256.f);
            float rs = rsqrtf(s2 * (1.f / 256.f) - mu * mu + 1e-5f);
#pragma unroll
            for (int ni = 0; ni < 4; ni++) {
                int c = wid * 64 + ni * 16 + l15;
                out[row * 256 + c] = (acc[ni][r] - mu) * rs * gv[ni] + bv[ni];
            }
        }
    }
}

extern "C" void kernel_launch(void* const* d_in, const int* in_sizes, int n_in,
                              void* d_out, int out_size, void* d_ws, size_t ws_size,
                              hipStream_t stream) {
    const int* leaf_ids = (const int*)d_in[0];
    const int* op_ids = (const int*)d_in[1];
    const float* tok = (const float*)d_in[2];
    const float* dep = (const float*)d_in[3];
    const float* idx = (const float*)d_in[4];
    const float* W = (const float*)d_in[5];
    const float* bvec = (const float*)d_in[6];
    const float* gamma = (const float*)d_in[7];
    const float* beta = (const float*)d_in[8];
    float* out = (float*)d_out;

    char* ws = (char*)d_ws;
    float* T = (float*)(ws);                                             // 3 MB (T0|T1|T2)
    unsigned short* WTbf = (unsigned short*)(ws + 3u * 1024 * 1024);     // 384 KB
    unsigned short* tokbf = (unsigned short*)(ws + 3u * 1024 * 1024 + 512 * 1024);  // 512 KB
    float* carr = (float*)(ws + 4u * 1024 * 1024 + 64 * 1024);           // 14 KB
    float* carrp = (float*)(ws + 5u * 1024 * 1024);                      // 112 KB partials
    unsigned short* mid = (unsigned short*)(ws + 6u * 1024 * 1024);      // 8 KB
    unsigned short* ebufA = (unsigned short*)(ws + 8u * 1024 * 1024);    // 16 MB
    unsigned short* ebufB = (unsigned short*)(ws + 40u * 1024 * 1024);   // 8 MB

    k_prep<<<416, 256, 0, stream>>>(tok, W, dep, idx, bvec, tokbf, WTbf, carrp);
    k_carrsum<<<14, 256, 0, stream>>>(carrp, carr);
    k_ttmm<<<dim3(32, 3), 256, 0, stream>>>(tokbf, WTbf, T);

    // levels 13+12 -> ebufA (4096 rows/batch), 32 rows/block
    k_level12f<<<dim3(128, 8), 256, 0, stream>>>(leaf_ids, op_ids, T, carr, gamma, beta, WTbf,
                                                 ebufA);
    // level 11 -> ebufB (2048 rows/batch)
    k_level<4><<<dim3(32, 8), 256, 0, stream>>>(ebufA, ebufB, op_ids, T, carr + 11 * 256, gamma,
                                                beta, WTbf, 2048);
    // level 10 -> ebufA (1024 rows/batch)
    k_level<2><<<dim3(32, 8), 256, 0, stream>>>(ebufB, ebufA, op_ids, T, carr + 10 * 256, gamma,
                                                beta, WTbf, 1024);
    // level 9 -> ebufB (512 rows/batch)
    k_level<2><<<dim3(16, 8), 256, 0, stream>>>(ebufA, ebufB, op_ids, T, carr + 9 * 256, gamma,
                                                beta, WTbf, 512);
    // level 8 -> ebufA (256 rows/batch)
    k_level<2><<<dim3(8, 8), 256, 0, stream>>>(ebufB, ebufA, op_ids, T, carr + 8 * 256, gamma,
                                               beta, WTbf, 256);
    // levels 7..1 (16 blocks: batch x subtree-half) -> mid
    k_tail<<<16, 512, 0, stream>>>(ebufA, op_ids, T, carr, gamma, beta, WTbf, mid);
    // level 0
    k_root<<<1, 256, 0, stream>>>(mid, op_ids, T, carr, gamma, beta, WTbf, out);
}